// Round 7
// baseline (144.420 us; speedup 1.0000x reference)
//
#include <hip/hip_runtime.h>

// ---------------------------------------------------------------------------
// SymmetricCrossAttention, B=4, C=64, H=W=256, HEADS=1.
// out1 = M1 X2 + c1 + X1, out2 = M2 X1 + c2 + X2 with M,c derived from
// G12 = X1 X2^T (64x64 per batch) + channel sums (k_gram/k_reduce/k_mid).
// R7 (occupancy round):
//  - k_apply: 256thr / 32KB LDS (other-side tile only; residual from global,
//    L3-resident) -> 5 blocks/CU, 62% occ (was 2 blocks/CU, 37%, 82us).
//  - k_gram: 512thr, 2 k-groups each own 32KB tile dbuf half -> 16 waves/CU
//    (was 8); cross-group acc+sum exchange once via LDS. WS layout unchanged.
// ---------------------------------------------------------------------------

#define NPIX 65536
#define SCALE 0.125f
#define NBLK_GRAM 512      // 4 batches * 128 chunks (512 px each)

// workspace float offsets (unchanged since R2 -- ws_size proven >= 8.85MB)
#define GP_OFF  0                      // 512 * 4096 partial Grams
#define SP_OFF  2097152                // 512 * 128 partial channel sums (s1|s2)
#define G_OFF   2162688                // 4 * 4096
#define S1_OFF  2179072                // 4 * 64
#define S2_OFF  2179328                // 4 * 64
#define MT_OFF  2179584                // 2*4*4096, M stored transposed Mt[j][o]
#define CV_OFF  2212352                // 2*4*64
#define WS_FLOATS 2212864              // ~8.85 MB

typedef __attribute__((ext_vector_type(8))) short bf16x8;  // 4 VGPR A/B frag
typedef __attribute__((ext_vector_type(4))) float f32x4;   // 16x16 C/D frag

// ---- XOR-swizzled 64x64 fp32 LDS tile helpers (16B-block index ^ (row>>2)&7)
__device__ __forceinline__ int swzidx(int row, int k) {
  return (row << 6) + ((((k >> 2) ^ ((row >> 2) & 7)) << 2) | (k & 3));
}
__device__ __forceinline__ float ldswz1(const float* b, int row, int k) {
  return b[swzidx(row, k)];
}
__device__ __forceinline__ void stswz1(float* b, int row, int k, float v) {
  b[swzidx(row, k)] = v;
}
__device__ __forceinline__ float4 ldswz4f(const float* b, int row, int k) { // k%4==0
  return *(const float4*)(b + (row << 6) + ((((k >> 2) ^ ((row >> 2) & 7)) << 2)));
}
__device__ __forceinline__ void stswz4f(float* b, int row, int k, float4 v) {
  *(float4*)(b + (row << 6) + ((((k >> 2) ^ ((row >> 2) & 7)) << 2))) = v;
}

// ---- async global->LDS 16B (wave-uniform LDS base + lane*16; global per-lane)
__device__ __forceinline__ void gload_lds16(const float* g, float* l) {
  __builtin_amdgcn_global_load_lds(
      (const __attribute__((address_space(1))) unsigned int*)g,
      (__attribute__((address_space(3))) unsigned int*)l, 16, 0, 0);
}

// ---- fp32 -> bf16 hi/lo split (truncation; lo captures next 16 mantissa bits)
__device__ __forceinline__ void cvt_hilo(float4 p, float4 q, bf16x8& hi, bf16x8& lo) {
  float x[8] = {p.x, p.y, p.z, p.w, q.x, q.y, q.z, q.w};
#pragma unroll
  for (int j = 0; j < 8; ++j) {
    const unsigned u = __float_as_uint(x[j]);
    const float hf = __uint_as_float(u & 0xFFFF0000u);
    hi[j] = (short)(u >> 16);
    lo[j] = (short)(__float_as_uint(x[j] - hf) >> 16);
  }
}

// ---------------------------------------------------------------------------
// Gram kernel (MFMA, R7): per batch, G12 = X1 X2^T (64x64) + channel sums.
// 512 blocks = 4 batches * 128 chunks of 512 px. 512 thr = 2 k-groups x 4
// waves. Group g owns px half [g*256, g*256+256) as 4 tiles of 64 px in its
// own 32KB LDS half (dbuf-by-group). Cross-group combine via LDS at end.
__global__ __launch_bounds__(512) void k_gram(const float* __restrict__ x1,
                                              const float* __restrict__ x2,
                                              float* __restrict__ gp,
                                              float* __restrict__ sp) {
  __shared__ __align__(16) float X1s[2][4096];
  __shared__ __align__(16) float X2s[2][4096];
  const int tid = threadIdx.x;
  const int b = blockIdx.x >> 7;
  const int chunk = blockIdx.x & 127;

  const int w = tid >> 6;          // wave 0..7
  const int grp = w >> 2;          // k-group
  const int wl = w & 3;            // wave-in-group -> G row-block
  const int l = tid & 63;
  const int lrow = l & 15;         // A row / B col within 16
  const int lkg = l >> 4;          // k-group-of-8 within frag
  const int arow = (wl << 4) + lrow;
  // group's 256-px half of the 512-px chunk
  const size_t base = ((size_t)b << 22) + ((size_t)chunk << 9) + (grp << 8);

  f32x4 acc[4] = {};               // 4 col-tiles of wave's 16x64 G strip
  float s_own = 0.f;               // channel-sum piece (half a row per thread)
  const int gtid = tid & 255;      // thread-in-group
  const int srow128 = gtid >> 1;   // 0..127: 0-63 -> X1 ch, 64-127 -> X2 ch
  const int sr = srow128 & 63;
  const float* sarr = (srow128 < 64) ? X1s[grp] : X2s[grp];
  const int shalf = (gtid & 1) << 3;

  for (int t = 0; t < 4; ++t) {
    __syncthreads();  // previous tile fully consumed (both groups)
    // stage group's 64-px tile: wave wl stages 1KB chunks 4wl..4wl+3
#pragma unroll
    for (int q = 0; q < 4; ++q) {
      const int ck = (wl << 2) + q;             // 1KB chunk 0..15
      const int c = (ck << 2) + lkg;            // channel row
      const int kb = lrow;                      // LDS px-block this lane fills
      const size_t off = base + ((size_t)c << 16) + (t << 6) + ((kb ^ (c & 7)) << 2);
      gload_lds16(x1 + off, &X1s[grp][ck << 8]);
      gload_lds16(x2 + off, &X2s[grp][ck << 8]);
    }
    __syncthreads();  // barrier drains vmcnt -> tile ready

    // channel sums over this group's tile
#pragma unroll
    for (int j = 0; j < 8; ++j) {
      const int kb2 = (shalf + j) ^ (sr & 7);
      const float4 v = *(const float4*)&sarr[(sr << 6) + (kb2 << 2)];
      s_own += v.x + v.y + v.z + v.w;
    }

    // MFMA: 2 k-steps of 32 px
#pragma unroll
    for (int ks = 0; ks < 2; ++ks) {
      const int kb0 = (ks << 3) + (lkg << 1);   // desired px-block pair
      bf16x8 ahi, alo;
      {
        const float4 p = *(const float4*)&X1s[grp][(arow << 6) + ((kb0 ^ (arow & 7)) << 2)];
        const float4 q2 = *(const float4*)&X1s[grp][(arow << 6) + (((kb0 + 1) ^ (arow & 7)) << 2)];
        cvt_hilo(p, q2, ahi, alo);
      }
#pragma unroll
      for (int n = 0; n < 4; ++n) {
        const int brow = (n << 4) + lrow;
        const float4 p = *(const float4*)&X2s[grp][(brow << 6) + ((kb0 ^ (brow & 7)) << 2)];
        const float4 q2 = *(const float4*)&X2s[grp][(brow << 6) + (((kb0 + 1) ^ (brow & 7)) << 2)];
        bf16x8 bhi, blo;
        cvt_hilo(p, q2, bhi, blo);
        acc[n] = __builtin_amdgcn_mfma_f32_16x16x32_bf16(ahi, bhi, acc[n], 0, 0, 0);
        acc[n] = __builtin_amdgcn_mfma_f32_16x16x32_bf16(ahi, blo, acc[n], 0, 0, 0);
        acc[n] = __builtin_amdgcn_mfma_f32_16x16x32_bf16(alo, bhi, acc[n], 0, 0, 0);
      }
    }
  }

  // ---- cross-group combine (tiles all consumed; LDS free) ----
  __syncthreads();
  const float so = s_own + __shfl_xor(s_own, 1);  // pair-reduce row halves
  float* exA = &X1s[0][0];                        // 4096 floats = acc exchange
  float* exS = &X2s[0][0];                        // 128 floats = sum exchange
  if (grp == 1) {
#pragma unroll
    for (int n = 0; n < 4; ++n) {
      *(float4*)&exA[((n << 8) + (wl << 6) + l) << 2] =
          make_float4(acc[n][0], acc[n][1], acc[n][2], acc[n][3]);
    }
    if ((gtid & 1) == 0) exS[srow128] = so;
  }
  __syncthreads();
  if (grp == 0) {
#pragma unroll
    for (int n = 0; n < 4; ++n) {
      const float4 v = *(const float4*)&exA[((n << 8) + (wl << 6) + l) << 2];
      acc[n][0] += v.x; acc[n][1] += v.y; acc[n][2] += v.z; acc[n][3] += v.w;
    }
    if ((gtid & 1) == 0) sp[(blockIdx.x << 7) + srow128] = so + exS[srow128];
    // G partial: C/D layout col=lane&15, row=(lane>>4)*4+reg (m89-verified)
    float* g = gp + ((size_t)blockIdx.x << 12);
#pragma unroll
    for (int n = 0; n < 4; ++n) {
#pragma unroll
      for (int r = 0; r < 4; ++r) {
        g[(((wl << 4) + (lkg << 2) + r) << 6) + (n << 4) + lrow] = acc[n][r];
      }
    }
  }
}

// ---------------------------------------------------------------------------
// Reduce 128 partials per batch into final G and channel sums.
__global__ __launch_bounds__(256) void k_reduce(float* __restrict__ ws) {
  const int g = blockIdx.x;
  const int tid = threadIdx.x;
  if (g < 64) {
    const int idx = (g << 8) + tid;            // 0..16383
    const int b = idx >> 12, e = idx & 4095;
    const float* p = ws + GP_OFF + (((size_t)b << 7) << 12) + e;
    float a = 0.f;
#pragma unroll 8
    for (int k = 0; k < 128; ++k) a += p[(size_t)k << 12];
    ws[G_OFF + idx] = a;
  } else {
    const int b = g - 64;
    if (tid < 128) {
      const float* p = ws + SP_OFF + ((b << 7) << 7) + tid;
      float a = 0.f;
#pragma unroll 8
      for (int k = 0; k < 128; ++k) a += p[k << 7];
      if (tid < 64) ws[S1_OFF + (b << 6) + tid] = a;
      else          ws[S2_OFF + (b << 6) + (tid - 64)] = a;
    }
  }
}

// ---------------------------------------------------------------------------
// 64x64 fp32 matmul in swizzled LDS. D[c][d] = sum_k A[c][k] * (TRANSB ? B[d][k] : B[k][d])
template <bool TRANSB>
__device__ __forceinline__ void mm64(const float* __restrict__ A, const float* __restrict__ B,
                                     float* __restrict__ D, int tid) {
  const int c0 = (tid >> 4) << 2;
  const int d0 = (tid & 15) << 2;
  float acc[4][4] = {{0.f}};
#pragma unroll
  for (int kb = 0; kb < 64; kb += 4) {
    float4 a[4];
#pragma unroll
    for (int i = 0; i < 4; ++i) a[i] = ldswz4f(A, c0 + i, kb);
    if (TRANSB) {
#pragma unroll
      for (int j = 0; j < 4; ++j) {
        const float4 bj = ldswz4f(B, d0 + j, kb);
#pragma unroll
        for (int i = 0; i < 4; ++i) {
          acc[i][j] += a[i].x * bj.x + a[i].y * bj.y + a[i].z * bj.z + a[i].w * bj.w;
        }
      }
    } else {
#pragma unroll
      for (int r = 0; r < 4; ++r) {
        const float4 q = ldswz4f(B, kb + r, d0);
        const float br[4] = {q.x, q.y, q.z, q.w};
#pragma unroll
        for (int i = 0; i < 4; ++i) {
          const float av = (r == 0) ? a[i].x : (r == 1) ? a[i].y : (r == 2) ? a[i].z : a[i].w;
#pragma unroll
          for (int j = 0; j < 4; ++j) acc[i][j] += av * br[j];
        }
      }
    }
  }
#pragma unroll
  for (int i = 0; i < 4; ++i) {
    stswz4f(D, c0 + i, d0, make_float4(acc[i][0], acc[i][1], acc[i][2], acc[i][3]));
  }
}

// M = A @ B (non-trans), stored TRANSPOSED to global: Mt[j][o] = M[o][j]
__device__ __forceinline__ void mm64_storeT(const float* __restrict__ A, const float* __restrict__ B,
                                            float* __restrict__ Mt, int tid) {
  const int c0 = (tid >> 4) << 2;
  const int d0 = (tid & 15) << 2;
  float acc[4][4] = {{0.f}};
#pragma unroll
  for (int kb = 0; kb < 64; kb += 4) {
    float4 a[4];
#pragma unroll
    for (int i = 0; i < 4; ++i) a[i] = ldswz4f(A, c0 + i, kb);
#pragma unroll
    for (int r = 0; r < 4; ++r) {
      const float4 q = ldswz4f(B, kb + r, d0);
      const float br[4] = {q.x, q.y, q.z, q.w};
#pragma unroll
      for (int i = 0; i < 4; ++i) {
        const float av = (r == 0) ? a[i].x : (r == 1) ? a[i].y : (r == 2) ? a[i].z : a[i].w;
#pragma unroll
        for (int j = 0; j < 4; ++j) acc[i][j] += av * br[j];
      }
    }
  }
#pragma unroll
  for (int i = 0; i < 4; ++i) {
#pragma unroll
    for (int j = 0; j < 4; ++j) {
      Mt[((d0 + j) << 6) + c0 + i] = acc[i][j];
    }
  }
}

__device__ __forceinline__ void load64x64(const float* __restrict__ g, float* __restrict__ lds, int tid) {
#pragma unroll
  for (int r = 0; r < 4; ++r) {
    const int idx = (r << 8) + tid;
    const int row = idx >> 4;
    const int b4 = (idx & 15) << 2;
    stswz4f(lds, row, b4, *(const float4*)(g + (row << 6) + b4));
  }
}

// ---------------------------------------------------------------------------
// Middle kernel: 8 blocks = 4 batches x 2 sides. Builds logits from G/s,
// softmax, then M (transposed) and c vectors into ws.
__global__ __launch_bounds__(256) void k_mid(
    const float* __restrict__ wq1, const float* __restrict__ bq1,
    const float* __restrict__ wk2, const float* __restrict__ bk2,
    const float* __restrict__ wv2, const float* __restrict__ bv2,
    const float* __restrict__ wo1, const float* __restrict__ bo1,
    const float* __restrict__ wq2, const float* __restrict__ bq2,
    const float* __restrict__ wk1, const float* __restrict__ bk1,
    const float* __restrict__ wv1, const float* __restrict__ bv1,
    const float* __restrict__ wo2, const float* __restrict__ bo2,
    float* __restrict__ ws) {
  __shared__ __align__(16) float LA[4096];
  __shared__ __align__(16) float LB[4096];
  __shared__ __align__(16) float LC[4096];
  __shared__ __align__(16) float LD[4096];
  __shared__ float vsq[64], vsk[64], vaq[64], vkk[64], vcv[64];

  const int tid = threadIdx.x;
  const int b = blockIdx.x >> 1;
  const int side = blockIdx.x & 1;

  const float *Wq, *Bq, *Wk, *Bk, *Wv, *Bv, *Wo, *Bo, *sqp, *skp;
  if (side == 0) {
    Wq = wq1; Bq = bq1; Wk = wk2; Bk = bk2; Wv = wv2; Bv = bv2; Wo = wo1; Bo = bo1;
    sqp = ws + S1_OFF + (b << 6); skp = ws + S2_OFF + (b << 6);
  } else {
    Wq = wq2; Bq = bq2; Wk = wk1; Bk = bk1; Wv = wv1; Bv = bv1; Wo = wo2; Bo = bo2;
    sqp = ws + S2_OFF + (b << 6); skp = ws + S1_OFF + (b << 6);
  }
  float* Mt = ws + MT_OFF + (((side << 2) + b) << 12);
  float* Cv = ws + CV_OFF + (((side << 2) + b) << 6);
  const float* G = ws + G_OFF + (b << 12);

  if (tid < 64) { vsq[tid] = sqp[tid]; vsk[tid] = skp[tid]; }
  load64x64(G, LA, tid);
  load64x64(Wq, LB, tid);
  __syncthreads();
  if (tid < 64) {  // aq = Wq @ sq
    float a = 0.f;
    for (int k = 0; k < 64; ++k) a += ldswz1(LB, tid, k) * vsq[k];
    vaq[tid] = a;
  }
  // T = Wq @ G (side0)  or  Wq @ G^T (side1)
  if (side == 0) mm64<false>(LB, LA, LC, tid);
  else           mm64<true >(LB, LA, LC, tid);
  __syncthreads();
  load64x64(Wk, LB, tid);
  __syncthreads();
  if (tid < 64) {  // kk = Wk @ sk
    float a = 0.f;
    for (int k = 0; k < 64; ++k) a += ldswz1(LB, tid, k) * vsk[k];
    vkk[tid] = a;
  }
  mm64<true>(LC, LB, LD, tid);  // S = T @ Wk^T
  __syncthreads();
  // assemble logits: S = scale*(S + aq[c]*bk[d] + bq[c]*(kk[d] + N*bk[d]))
#pragma unroll
  for (int t = 0; t < 16; ++t) {
    const int idx = (t << 8) + tid;
    const int c = idx >> 6, d = idx & 63;
    const float bkv = Bk[d], bqv = Bq[c];
    float v = ldswz1(LD, c, d);
    v = SCALE * (v + vaq[c] * bkv + bqv * (vkk[d] + 65536.f * bkv));
    stswz1(LD, c, d, v);
  }
  __syncthreads();
  {  // row softmax, 4 lanes per row
    const int row = tid >> 2, q = tid & 3;
    float ev[16];
    float mx = -3.4e38f;
#pragma unroll
    for (int t = 0; t < 16; ++t) { ev[t] = ldswz1(LD, row, q + (t << 2)); mx = fmaxf(mx, ev[t]); }
    mx = fmaxf(mx, __shfl_xor(mx, 1));
    mx = fmaxf(mx, __shfl_xor(mx, 2));
    float sm = 0.f;
#pragma unroll
    for (int t = 0; t < 16; ++t) { ev[t] = __expf(ev[t] - mx); sm += ev[t]; }
    sm += __shfl_xor(sm, 1);
    sm += __shfl_xor(sm, 2);
    const float inv = 1.f / sm;
#pragma unroll
    for (int t = 0; t < 16; ++t) stswz1(LD, row, q + (t << 2), ev[t] * inv);
  }
  __syncthreads();
  if (tid < 64) {  // cv = attn @ bv
    float a = 0.f;
    for (int d = 0; d < 64; ++d) a += ldswz1(LD, tid, d) * Bv[d];
    vcv[tid] = a;
  }
  load64x64(Wv, LB, tid);
  __syncthreads();
  mm64<false>(LD, LB, LC, tid);  // U = attn @ Wv
  __syncthreads();
  load64x64(Wo, LB, tid);
  __syncthreads();
  mm64_storeT(LB, LC, Mt, tid);  // Mt[j][o] = (Wo @ U)[o][j]
  if (tid < 64) {                // c = Wo @ cv + bo
    float a = 0.f;
    for (int c = 0; c < 64; ++c) a += ldswz1(LB, tid, c) * vcv[c];
    Cv[tid] = a + Bo[tid];
  }
}

// ---------------------------------------------------------------------------
// Apply kernel (R7): 4096 blocks = 2 sides x 4 batches x 512 tiles(128px).
// 256 thr / 4 waves / 32KB LDS (other side's tile only -> 5 blocks/CU).
// Wave w owns out-ch chunk oc = w*16 (uniform -> M rows s_load); residual
// read from global (L3-resident, coalesced). Lane owns a px pair.
__global__ __launch_bounds__(256) void k_apply(const float* __restrict__ x1,
                                               const float* __restrict__ x2,
                                               const float* __restrict__ ws,
                                               float* __restrict__ out) {
  __shared__ __align__(16) float Xs[8192];  // other side [64ch][128px]
  const int tid = threadIdx.x;
  const int side = blockIdx.x >> 11;
  const int b = (blockIdx.x >> 9) & 3;
  const int tile = blockIdx.x & 511;
  const size_t ib = ((size_t)b << 22) + ((size_t)tile << 7);
  const float* xoth = side ? x1 : x2;
  const float* xown = side ? x2 : x1;

  const int w = tid >> 6;
  const int l = tid & 63;

  // stage other-side tile: 32 chunks of 1KB (2 ch x 128 px); wave w: 8 chunks
#pragma unroll
  for (int q = 0; q < 8; ++q) {
    const int ck = (w << 3) + q;
    const int c = (ck << 1) | (l >> 5);
    const int p4 = l & 31;
    gload_lds16(xoth + ib + ((size_t)c << 16) + (p4 << 2), &Xs[ck << 8]);
  }
  __syncthreads();  // barrier drains vmcnt -> tile ready

  const int wu = __builtin_amdgcn_readfirstlane(w);
  const int oc = wu << 4;
  const int job = (side << 2) + b;
  const float* Mt = ws + MT_OFF + ((size_t)job << 12);  // Mt[j][o]
  const float* Cv = ws + CV_OFF + (job << 6);
  const int p0 = l << 1;

  float acc[16][2];
#pragma unroll
  for (int oi = 0; oi < 16; ++oi) {
    const float cb = Cv[oc + oi];
    const float2 xr = *(const float2*)&xown[((size_t)(oc + oi) << 16) + ib + p0];
    acc[oi][0] = cb + xr.x;               // bias + residual
    acc[oi][1] = cb + xr.y;
  }

#pragma unroll 2
  for (int j = 0; j < 64; ++j) {
    const float2 xo = *(const float2*)&Xs[(j << 7) + p0];
    const float* mrow = Mt + (j << 6) + oc;  // wave-uniform -> s_load
#pragma unroll
    for (int oi = 0; oi < 16; ++oi) {
      acc[oi][0] += mrow[oi] * xo.x;
      acc[oi][1] += mrow[oi] * xo.y;
    }
  }

  float* o = out + ((size_t)side << 24) + ib + p0;
#pragma unroll
  for (int oi = 0; oi < 16; ++oi) {
    *(float2*)&o[(size_t)(oc + oi) << 16] = make_float2(acc[oi][0], acc[oi][1]);
  }
}

// ---------------------------------------------------------------------------
extern "C" void kernel_launch(void* const* d_in, const int* in_sizes, int n_in,
                              void* d_out, int out_size, void* d_ws, size_t ws_size,
                              hipStream_t stream) {
  const float* x1 = (const float*)d_in[0];
  const float* x2 = (const float*)d_in[1];
  float* ws = (float*)d_ws;
  float* out = (float*)d_out;

  k_gram<<<NBLK_GRAM, 512, 0, stream>>>(x1, x2, ws + GP_OFF, ws + SP_OFF);
  k_reduce<<<68, 256, 0, stream>>>(ws);
  k_mid<<<8, 256, 0, stream>>>(
      (const float*)d_in[2],  (const float*)d_in[3],   // w_q1, b_q1
      (const float*)d_in[4],  (const float*)d_in[5],   // w_k2, b_k2
      (const float*)d_in[6],  (const float*)d_in[7],   // w_v2, b_v2
      (const float*)d_in[14], (const float*)d_in[15],  // w_o1, b_o1
      (const float*)d_in[8],  (const float*)d_in[9],   // w_q2, b_q2
      (const float*)d_in[10], (const float*)d_in[11],  // w_k1, b_k1
      (const float*)d_in[12], (const float*)d_in[13],  // w_v1, b_v1
      (const float*)d_in[16], (const float*)d_in[17],  // w_o2, b_o2
      ws);
  k_apply<<<4096, 256, 0, stream>>>(x1, x2, ws, out);
}

// Round 8
// 131.440 us; speedup vs baseline: 1.0988x; 1.0988x over previous
//
#include <hip/hip_runtime.h>

// ---------------------------------------------------------------------------
// SymmetricCrossAttention, B=4, C=64, H=W=256, HEADS=1.
// out1 = M1 X2 + c1 + X1, out2 = M2 X1 + c2 + X2 with M,c derived from
// G12 = X1 X2^T (64x64 per batch) + channel sums (k_gram/k_reduce/k_mid).
// R8: k_apply -> software-pipelined double buffer (T3/T4 pattern):
//     64-px half-tiles, both sides staged (minimal 268MB traffic), counted
//     s_waitcnt vmcnt(16) + raw s_barrier (never drain-0 mid-loop), stage
//     of half h+1 overlaps compute of half h. 512 blocks x 512thr, 64KB LDS
//     -> exactly 2 blocks/CU, no tail. Was: serial stage->drain->compute,
//     94us at 32% VALUBusy (R7) / 82us (R6).
// ---------------------------------------------------------------------------

#define NPIX 65536
#define SCALE 0.125f
#define NBLK_GRAM 512      // 4 batches * 128 chunks (512 px each)

// workspace float offsets (unchanged since R2 -- ws_size proven >= 8.85MB)
#define GP_OFF  0                      // 512 * 4096 partial Grams
#define SP_OFF  2097152                // 512 * 128 partial channel sums (s1|s2)
#define G_OFF   2162688                // 4 * 4096
#define S1_OFF  2179072                // 4 * 64
#define S2_OFF  2179328                // 4 * 64
#define MT_OFF  2179584                // 2*4*4096, M stored transposed Mt[j][o]
#define CV_OFF  2212352                // 2*4*64
#define WS_FLOATS 2212864              // ~8.85 MB

typedef __attribute__((ext_vector_type(8))) short bf16x8;  // 4 VGPR A/B frag
typedef __attribute__((ext_vector_type(4))) float f32x4;   // 16x16 C/D frag

// ---- XOR-swizzled 64x64 fp32 LDS tile helpers (16B-block index ^ (row>>2)&7)
__device__ __forceinline__ int swzidx(int row, int k) {
  return (row << 6) + ((((k >> 2) ^ ((row >> 2) & 7)) << 2) | (k & 3));
}
__device__ __forceinline__ float ldswz1(const float* b, int row, int k) {
  return b[swzidx(row, k)];
}
__device__ __forceinline__ void stswz1(float* b, int row, int k, float v) {
  b[swzidx(row, k)] = v;
}
__device__ __forceinline__ float4 ldswz4f(const float* b, int row, int k) { // k%4==0
  return *(const float4*)(b + (row << 6) + ((((k >> 2) ^ ((row >> 2) & 7)) << 2)));
}
__device__ __forceinline__ void stswz4f(float* b, int row, int k, float4 v) {
  *(float4*)(b + (row << 6) + ((((k >> 2) ^ ((row >> 2) & 7)) << 2))) = v;
}

// ---- async global->LDS 16B (wave-uniform LDS base + lane*16; global per-lane)
__device__ __forceinline__ void gload_lds16(const float* g, float* l) {
  __builtin_amdgcn_global_load_lds(
      (const __attribute__((address_space(1))) unsigned int*)g,
      (__attribute__((address_space(3))) unsigned int*)l, 16, 0, 0);
}

// ---- fp32 -> bf16 hi/lo split (truncation; lo captures next 16 mantissa bits)
__device__ __forceinline__ void cvt_hilo(float4 p, float4 q, bf16x8& hi, bf16x8& lo) {
  float x[8] = {p.x, p.y, p.z, p.w, q.x, q.y, q.z, q.w};
#pragma unroll
  for (int j = 0; j < 8; ++j) {
    const unsigned u = __float_as_uint(x[j]);
    const float hf = __uint_as_float(u & 0xFFFF0000u);
    hi[j] = (short)(u >> 16);
    lo[j] = (short)(__float_as_uint(x[j] - hf) >> 16);
  }
}

// ---------------------------------------------------------------------------
// Gram kernel (MFMA): per batch, G12 = X1 X2^T (64x64) + channel sums.
// 512 blocks = 4 batches * 128 chunks of 512 px. 512 thr = 2 k-groups x 4
// waves. Group g owns px half [g*256, g*256+256) as 4 tiles of 64 px in its
// own 32KB LDS half. Cross-group combine via LDS at end.
__global__ __launch_bounds__(512) void k_gram(const float* __restrict__ x1,
                                              const float* __restrict__ x2,
                                              float* __restrict__ gp,
                                              float* __restrict__ sp) {
  __shared__ __align__(16) float X1s[2][4096];
  __shared__ __align__(16) float X2s[2][4096];
  const int tid = threadIdx.x;
  const int b = blockIdx.x >> 7;
  const int chunk = blockIdx.x & 127;

  const int w = tid >> 6;          // wave 0..7
  const int grp = w >> 2;          // k-group
  const int wl = w & 3;            // wave-in-group -> G row-block
  const int l = tid & 63;
  const int lrow = l & 15;         // A row / B col within 16
  const int lkg = l >> 4;          // k-group-of-8 within frag
  const int arow = (wl << 4) + lrow;
  // group's 256-px half of the 512-px chunk
  const size_t base = ((size_t)b << 22) + ((size_t)chunk << 9) + (grp << 8);

  f32x4 acc[4] = {};               // 4 col-tiles of wave's 16x64 G strip
  float s_own = 0.f;               // channel-sum piece (half a row per thread)
  const int gtid = tid & 255;      // thread-in-group
  const int srow128 = gtid >> 1;   // 0..127: 0-63 -> X1 ch, 64-127 -> X2 ch
  const int sr = srow128 & 63;
  const float* sarr = (srow128 < 64) ? X1s[grp] : X2s[grp];
  const int shalf = (gtid & 1) << 3;

  for (int t = 0; t < 4; ++t) {
    __syncthreads();  // previous tile fully consumed (both groups)
    // stage group's 64-px tile: wave wl stages 1KB chunks 4wl..4wl+3
#pragma unroll
    for (int q = 0; q < 4; ++q) {
      const int ck = (wl << 2) + q;             // 1KB chunk 0..15
      const int c = (ck << 2) + lkg;            // channel row
      const int kb = lrow;                      // LDS px-block this lane fills
      const size_t off = base + ((size_t)c << 16) + (t << 6) + ((kb ^ (c & 7)) << 2);
      gload_lds16(x1 + off, &X1s[grp][ck << 8]);
      gload_lds16(x2 + off, &X2s[grp][ck << 8]);
    }
    __syncthreads();  // barrier drains vmcnt -> tile ready

    // channel sums over this group's tile
#pragma unroll
    for (int j = 0; j < 8; ++j) {
      const int kb2 = (shalf + j) ^ (sr & 7);
      const float4 v = *(const float4*)&sarr[(sr << 6) + (kb2 << 2)];
      s_own += v.x + v.y + v.z + v.w;
    }

    // MFMA: 2 k-steps of 32 px
#pragma unroll
    for (int ks = 0; ks < 2; ++ks) {
      const int kb0 = (ks << 3) + (lkg << 1);   // desired px-block pair
      bf16x8 ahi, alo;
      {
        const float4 p = *(const float4*)&X1s[grp][(arow << 6) + ((kb0 ^ (arow & 7)) << 2)];
        const float4 q2 = *(const float4*)&X1s[grp][(arow << 6) + (((kb0 + 1) ^ (arow & 7)) << 2)];
        cvt_hilo(p, q2, ahi, alo);
      }
#pragma unroll
      for (int n = 0; n < 4; ++n) {
        const int brow = (n << 4) + lrow;
        const float4 p = *(const float4*)&X2s[grp][(brow << 6) + ((kb0 ^ (brow & 7)) << 2)];
        const float4 q2 = *(const float4*)&X2s[grp][(brow << 6) + (((kb0 + 1) ^ (brow & 7)) << 2)];
        bf16x8 bhi, blo;
        cvt_hilo(p, q2, bhi, blo);
        acc[n] = __builtin_amdgcn_mfma_f32_16x16x32_bf16(ahi, bhi, acc[n], 0, 0, 0);
        acc[n] = __builtin_amdgcn_mfma_f32_16x16x32_bf16(ahi, blo, acc[n], 0, 0, 0);
        acc[n] = __builtin_amdgcn_mfma_f32_16x16x32_bf16(alo, bhi, acc[n], 0, 0, 0);
      }
    }
  }

  // ---- cross-group combine (tiles all consumed; LDS free) ----
  __syncthreads();
  const float so = s_own + __shfl_xor(s_own, 1);  // pair-reduce row halves
  float* exA = &X1s[0][0];                        // 4096 floats = acc exchange
  float* exS = &X2s[0][0];                        // 128 floats = sum exchange
  if (grp == 1) {
#pragma unroll
    for (int n = 0; n < 4; ++n) {
      *(float4*)&exA[((n << 8) + (wl << 6) + l) << 2] =
          make_float4(acc[n][0], acc[n][1], acc[n][2], acc[n][3]);
    }
    if ((gtid & 1) == 0) exS[srow128] = so;
  }
  __syncthreads();
  if (grp == 0) {
#pragma unroll
    for (int n = 0; n < 4; ++n) {
      const float4 v = *(const float4*)&exA[((n << 8) + (wl << 6) + l) << 2];
      acc[n][0] += v.x; acc[n][1] += v.y; acc[n][2] += v.z; acc[n][3] += v.w;
    }
    if ((gtid & 1) == 0) sp[(blockIdx.x << 7) + srow128] = so + exS[srow128];
    // G partial: C/D layout col=lane&15, row=(lane>>4)*4+reg (m89-verified)
    float* g = gp + ((size_t)blockIdx.x << 12);
#pragma unroll
    for (int n = 0; n < 4; ++n) {
#pragma unroll
      for (int r = 0; r < 4; ++r) {
        g[(((wl << 4) + (lkg << 2) + r) << 6) + (n << 4) + lrow] = acc[n][r];
      }
    }
  }
}

// ---------------------------------------------------------------------------
// Reduce 128 partials per batch into final G and channel sums.
__global__ __launch_bounds__(256) void k_reduce(float* __restrict__ ws) {
  const int g = blockIdx.x;
  const int tid = threadIdx.x;
  if (g < 64) {
    const int idx = (g << 8) + tid;            // 0..16383
    const int b = idx >> 12, e = idx & 4095;
    const float* p = ws + GP_OFF + (((size_t)b << 7) << 12) + e;
    float a = 0.f;
#pragma unroll 8
    for (int k = 0; k < 128; ++k) a += p[(size_t)k << 12];
    ws[G_OFF + idx] = a;
  } else {
    const int b = g - 64;
    if (tid < 128) {
      const float* p = ws + SP_OFF + ((b << 7) << 7) + tid;
      float a = 0.f;
#pragma unroll 8
      for (int k = 0; k < 128; ++k) a += p[k << 7];
      if (tid < 64) ws[S1_OFF + (b << 6) + tid] = a;
      else          ws[S2_OFF + (b << 6) + (tid - 64)] = a;
    }
  }
}

// ---------------------------------------------------------------------------
// 64x64 fp32 matmul in swizzled LDS. D[c][d] = sum_k A[c][k] * (TRANSB ? B[d][k] : B[k][d])
template <bool TRANSB>
__device__ __forceinline__ void mm64(const float* __restrict__ A, const float* __restrict__ B,
                                     float* __restrict__ D, int tid) {
  const int c0 = (tid >> 4) << 2;
  const int d0 = (tid & 15) << 2;
  float acc[4][4] = {{0.f}};
#pragma unroll
  for (int kb = 0; kb < 64; kb += 4) {
    float4 a[4];
#pragma unroll
    for (int i = 0; i < 4; ++i) a[i] = ldswz4f(A, c0 + i, kb);
    if (TRANSB) {
#pragma unroll
      for (int j = 0; j < 4; ++j) {
        const float4 bj = ldswz4f(B, d0 + j, kb);
#pragma unroll
        for (int i = 0; i < 4; ++i) {
          acc[i][j] += a[i].x * bj.x + a[i].y * bj.y + a[i].z * bj.z + a[i].w * bj.w;
        }
      }
    } else {
#pragma unroll
      for (int r = 0; r < 4; ++r) {
        const float4 q = ldswz4f(B, kb + r, d0);
        const float br[4] = {q.x, q.y, q.z, q.w};
#pragma unroll
        for (int i = 0; i < 4; ++i) {
          const float av = (r == 0) ? a[i].x : (r == 1) ? a[i].y : (r == 2) ? a[i].z : a[i].w;
#pragma unroll
          for (int j = 0; j < 4; ++j) acc[i][j] += av * br[j];
        }
      }
    }
  }
#pragma unroll
  for (int i = 0; i < 4; ++i) {
    stswz4f(D, c0 + i, d0, make_float4(acc[i][0], acc[i][1], acc[i][2], acc[i][3]));
  }
}

// M = A @ B (non-trans), stored TRANSPOSED to global: Mt[j][o] = M[o][j]
__device__ __forceinline__ void mm64_storeT(const float* __restrict__ A, const float* __restrict__ B,
                                            float* __restrict__ Mt, int tid) {
  const int c0 = (tid >> 4) << 2;
  const int d0 = (tid & 15) << 2;
  float acc[4][4] = {{0.f}};
#pragma unroll
  for (int kb = 0; kb < 64; kb += 4) {
    float4 a[4];
#pragma unroll
    for (int i = 0; i < 4; ++i) a[i] = ldswz4f(A, c0 + i, kb);
#pragma unroll
    for (int r = 0; r < 4; ++r) {
      const float4 q = ldswz4f(B, kb + r, d0);
      const float br[4] = {q.x, q.y, q.z, q.w};
#pragma unroll
      for (int i = 0; i < 4; ++i) {
        const float av = (r == 0) ? a[i].x : (r == 1) ? a[i].y : (r == 2) ? a[i].z : a[i].w;
#pragma unroll
        for (int j = 0; j < 4; ++j) acc[i][j] += av * br[j];
      }
    }
  }
#pragma unroll
  for (int i = 0; i < 4; ++i) {
#pragma unroll
    for (int j = 0; j < 4; ++j) {
      Mt[((d0 + j) << 6) + c0 + i] = acc[i][j];
    }
  }
}

__device__ __forceinline__ void load64x64(const float* __restrict__ g, float* __restrict__ lds, int tid) {
#pragma unroll
  for (int r = 0; r < 4; ++r) {
    const int idx = (r << 8) + tid;
    const int row = idx >> 4;
    const int b4 = (idx & 15) << 2;
    stswz4f(lds, row, b4, *(const float4*)(g + (row << 6) + b4));
  }
}

// ---------------------------------------------------------------------------
// Middle kernel: 8 blocks = 4 batches x 2 sides. Builds logits from G/s,
// softmax, then M (transposed) and c vectors into ws.
__global__ __launch_bounds__(256) void k_mid(
    const float* __restrict__ wq1, const float* __restrict__ bq1,
    const float* __restrict__ wk2, const float* __restrict__ bk2,
    const float* __restrict__ wv2, const float* __restrict__ bv2,
    const float* __restrict__ wo1, const float* __restrict__ bo1,
    const float* __restrict__ wq2, const float* __restrict__ bq2,
    const float* __restrict__ wk1, const float* __restrict__ bk1,
    const float* __restrict__ wv1, const float* __restrict__ bv1,
    const float* __restrict__ wo2, const float* __restrict__ bo2,
    float* __restrict__ ws) {
  __shared__ __align__(16) float LA[4096];
  __shared__ __align__(16) float LB[4096];
  __shared__ __align__(16) float LC[4096];
  __shared__ __align__(16) float LD[4096];
  __shared__ float vsq[64], vsk[64], vaq[64], vkk[64], vcv[64];

  const int tid = threadIdx.x;
  const int b = blockIdx.x >> 1;
  const int side = blockIdx.x & 1;

  const float *Wq, *Bq, *Wk, *Bk, *Wv, *Bv, *Wo, *Bo, *sqp, *skp;
  if (side == 0) {
    Wq = wq1; Bq = bq1; Wk = wk2; Bk = bk2; Wv = wv2; Bv = bv2; Wo = wo1; Bo = bo1;
    sqp = ws + S1_OFF + (b << 6); skp = ws + S2_OFF + (b << 6);
  } else {
    Wq = wq2; Bq = bq2; Wk = wk1; Bk = bk1; Wv = wv1; Bv = bv1; Wo = wo2; Bo = bo2;
    sqp = ws + S2_OFF + (b << 6); skp = ws + S1_OFF + (b << 6);
  }
  float* Mt = ws + MT_OFF + (((side << 2) + b) << 12);
  float* Cv = ws + CV_OFF + (((side << 2) + b) << 6);
  const float* G = ws + G_OFF + (b << 12);

  if (tid < 64) { vsq[tid] = sqp[tid]; vsk[tid] = skp[tid]; }
  load64x64(G, LA, tid);
  load64x64(Wq, LB, tid);
  __syncthreads();
  if (tid < 64) {  // aq = Wq @ sq
    float a = 0.f;
    for (int k = 0; k < 64; ++k) a += ldswz1(LB, tid, k) * vsq[k];
    vaq[tid] = a;
  }
  // T = Wq @ G (side0)  or  Wq @ G^T (side1)
  if (side == 0) mm64<false>(LB, LA, LC, tid);
  else           mm64<true >(LB, LA, LC, tid);
  __syncthreads();
  load64x64(Wk, LB, tid);
  __syncthreads();
  if (tid < 64) {  // kk = Wk @ sk
    float a = 0.f;
    for (int k = 0; k < 64; ++k) a += ldswz1(LB, tid, k) * vsk[k];
    vkk[tid] = a;
  }
  mm64<true>(LC, LB, LD, tid);  // S = T @ Wk^T
  __syncthreads();
  // assemble logits: S = scale*(S + aq[c]*bk[d] + bq[c]*(kk[d] + N*bk[d]))
#pragma unroll
  for (int t = 0; t < 16; ++t) {
    const int idx = (t << 8) + tid;
    const int c = idx >> 6, d = idx & 63;
    const float bkv = Bk[d], bqv = Bq[c];
    float v = ldswz1(LD, c, d);
    v = SCALE * (v + vaq[c] * bkv + bqv * (vkk[d] + 65536.f * bkv));
    stswz1(LD, c, d, v);
  }
  __syncthreads();
  {  // row softmax, 4 lanes per row
    const int row = tid >> 2, q = tid & 3;
    float ev[16];
    float mx = -3.4e38f;
#pragma unroll
    for (int t = 0; t < 16; ++t) { ev[t] = ldswz1(LD, row, q + (t << 2)); mx = fmaxf(mx, ev[t]); }
    mx = fmaxf(mx, __shfl_xor(mx, 1));
    mx = fmaxf(mx, __shfl_xor(mx, 2));
    float sm = 0.f;
#pragma unroll
    for (int t = 0; t < 16; ++t) { ev[t] = __expf(ev[t] - mx); sm += ev[t]; }
    sm += __shfl_xor(sm, 1);
    sm += __shfl_xor(sm, 2);
    const float inv = 1.f / sm;
#pragma unroll
    for (int t = 0; t < 16; ++t) stswz1(LD, row, q + (t << 2), ev[t] * inv);
  }
  __syncthreads();
  if (tid < 64) {  // cv = attn @ bv
    float a = 0.f;
    for (int d = 0; d < 64; ++d) a += ldswz1(LD, tid, d) * Bv[d];
    vcv[tid] = a;
  }
  load64x64(Wv, LB, tid);
  __syncthreads();
  mm64<false>(LD, LB, LC, tid);  // U = attn @ Wv
  __syncthreads();
  load64x64(Wo, LB, tid);
  __syncthreads();
  mm64_storeT(LB, LC, Mt, tid);  // Mt[j][o] = (Wo @ U)[o][j]
  if (tid < 64) {                // c = Wo @ cv + bo
    float a = 0.f;
    for (int c = 0; c < 64; ++c) a += ldswz1(LB, tid, c) * vcv[c];
    Cv[tid] = a + Bo[tid];
  }
}

// ---------------------------------------------------------------------------
// Apply kernel (R8): 512 blocks x 512 thr; block owns 512 contiguous px of
// one batch, processed as 8 half-tiles of 64 px, double-buffered (2x32KB).
// Per half: both sides staged (64ch x 64px x 2). Wave w: side=w>>2,
// oc=(w&3)*16 (uniform -> M rows via s_load); lane owns 1 px.
// Pipeline: [wait vmcnt(16); s_barrier; stage(h+1); compute(h)] -- stage of
// next half overlaps compute of current; never drains vmcnt to 0 mid-loop.
__global__ __launch_bounds__(512) void k_apply(const float* __restrict__ x1,
                                               const float* __restrict__ x2,
                                               const float* __restrict__ ws,
                                               float* __restrict__ out) {
  __shared__ __align__(16) float buf[2][8192];  // [dbuf][side*4096 + ch*64 + px]
  const int tid = threadIdx.x;
  const int b = blockIdx.x >> 7;
  const int px_blk = (blockIdx.x & 127) << 9;   // 512 px per block
  const size_t bb = (size_t)b << 22;

  const int w = tid >> 6;
  const int l = tid & 63;
  const int wu = __builtin_amdgcn_readfirstlane(w);
  const int side = wu >> 2;
  const int oc = (wu & 3) << 4;
  const int job = (side << 2) + b;
  const float* Mt = ws + MT_OFF + ((size_t)job << 12);  // Mt[j][o]
  const float* Cv = ws + CV_OFF + (job << 6);

  // stage half h into buf[h&1]: 32 chunks of 1KB (4 ch-rows x 64 px each);
  // wave w fills chunks 4w..4w+3 (chunk>>4 = side). Linear dst, linear src.
#define STAGE_HALF(h)                                                         \
  {                                                                           \
    _Pragma("unroll") for (int q = 0; q < 4; ++q) {                           \
      const int ckk = (w << 2) + q;                                           \
      const int c = ((ckk & 15) << 2) + (l >> 4);                             \
      const size_t off = bb + ((size_t)c << 16) + px_blk + ((h) << 6) +       \
                         ((l & 15) << 2);                                     \
      gload_lds16(((ckk >> 4) ? x2 : x1) + off, &buf[(h) & 1][ckk << 8]);     \
    }                                                                         \
  }

  STAGE_HALF(0);

#pragma unroll 1
  for (int h = 0; h < 8; ++h) {
    if (h == 0) {
      asm volatile("s_waitcnt vmcnt(0)" ::: "memory");
    } else {
      // outstanding: 4 stage(h) loads (oldest) + 16 stores from compute(h-1)
      // (younger). In-order retirement: <=16 outstanding => stage(h) landed.
      asm volatile("s_waitcnt vmcnt(16)" ::: "memory");
    }
    __builtin_amdgcn_s_barrier();
    __builtin_amdgcn_sched_barrier(0);
    if (h + 1 < 8) STAGE_HALF(h + 1);
    __builtin_amdgcn_sched_barrier(0);  // pin stage issue before compute VMEM

    const float* bufc = buf[h & 1];
    const float* bo = bufc + ((side ^ 1) << 12);  // other side (cross input)
    const float* bw = bufc + (side << 12);        // own side (residual)
    float acc[16];
#pragma unroll
    for (int oi = 0; oi < 16; ++oi) {
      acc[oi] = Cv[oc + oi] + bw[((oc + oi) << 6) + l];
    }
#pragma unroll 4
    for (int j = 0; j < 64; ++j) {
      const float xo = bo[(j << 6) + l];
      const float* mrow = Mt + (j << 6) + oc;     // wave-uniform -> s_load
#pragma unroll
      for (int oi = 0; oi < 16; ++oi) acc[oi] += mrow[oi] * xo;
    }
    const size_t po = ((size_t)side << 24) + bb + px_blk + (h << 6) + l;
#pragma unroll
    for (int oi = 0; oi < 16; ++oi) {
      out[po + ((size_t)(oc + oi) << 16)] = acc[oi];
    }
  }
#undef STAGE_HALF
}

// ---------------------------------------------------------------------------
extern "C" void kernel_launch(void* const* d_in, const int* in_sizes, int n_in,
                              void* d_out, int out_size, void* d_ws, size_t ws_size,
                              hipStream_t stream) {
  const float* x1 = (const float*)d_in[0];
  const float* x2 = (const float*)d_in[1];
  float* ws = (float*)d_ws;
  float* out = (float*)d_out;

  k_gram<<<NBLK_GRAM, 512, 0, stream>>>(x1, x2, ws + GP_OFF, ws + SP_OFF);
  k_reduce<<<68, 256, 0, stream>>>(ws);
  k_mid<<<8, 256, 0, stream>>>(
      (const float*)d_in[2],  (const float*)d_in[3],   // w_q1, b_q1
      (const float*)d_in[4],  (const float*)d_in[5],   // w_k2, b_k2
      (const float*)d_in[6],  (const float*)d_in[7],   // w_v2, b_v2
      (const float*)d_in[14], (const float*)d_in[15],  // w_o1, b_o1
      (const float*)d_in[8],  (const float*)d_in[9],   // w_q2, b_q2
      (const float*)d_in[10], (const float*)d_in[11],  // w_k1, b_k1
      (const float*)d_in[12], (const float*)d_in[13],  // w_v1, b_v1
      (const float*)d_in[16], (const float*)d_in[17],  // w_o2, b_o2
      ws);
  k_apply<<<512, 512, 0, stream>>>(x1, x2, ws, out);
}

// Round 9
// 100.732 us; speedup vs baseline: 1.4337x; 1.3048x over previous
//
#include <hip/hip_runtime.h>

// ---------------------------------------------------------------------------
// SymmetricCrossAttention, B=4, C=64, H=W=256, HEADS=1.
// out1 = M1 X2 + c1 + X1, out2 = M2 X1 + c2 + X2 with M,c derived from
// G12 = X1 X2^T (64x64 per batch) + channel sums (k_gram/k_reduce/k_mid).
// R9: k_apply moved to MFMA. k_mid emits M as bf16 hi/lo (exact split,
//     aliased into the dead GP region); k_apply: 2 mfma/tile (Mh+Ml)*Xh,
//     M-frags resident in VGPRs across all halves, X-frags = 16 ds_read_b32
//     + truncate-to-bf16. Was: 1024 scalar FMA/wave/half = 29us VALU floor
//     (R8 80.6us, VALUBusy 41%). Dropped M*Xl term: ~0.005 abs error.
// ---------------------------------------------------------------------------

#define NPIX 65536
#define SCALE 0.125f
#define NBLK_GRAM 512      // 4 batches * 128 chunks (512 px each)

// workspace float offsets (unchanged since R2 -- ws_size proven >= 8.85MB)
#define GP_OFF  0                      // 512 * 4096 partial Grams (dead after
                                       // k_reduce; k_mid aliases MH/ML here)
#define SP_OFF  2097152                // 512 * 128 partial channel sums (s1|s2)
#define G_OFF   2162688                // 4 * 4096
#define S1_OFF  2179072                // 4 * 64
#define S2_OFF  2179328                // 4 * 64
#define MT_OFF  2179584                // (unused in R9)
#define CV_OFF  2212352                // 2*4*64
#define WS_FLOATS 2212864              // ~8.85 MB

typedef __attribute__((ext_vector_type(8))) short bf16x8;  // 4 VGPR A/B frag
typedef __attribute__((ext_vector_type(4))) float f32x4;   // 16x16 C/D frag

// ---- XOR-swizzled 64x64 fp32 LDS tile helpers (16B-block index ^ (row>>2)&7)
__device__ __forceinline__ int swzidx(int row, int k) {
  return (row << 6) + ((((k >> 2) ^ ((row >> 2) & 7)) << 2) | (k & 3));
}
__device__ __forceinline__ float ldswz1(const float* b, int row, int k) {
  return b[swzidx(row, k)];
}
__device__ __forceinline__ void stswz1(float* b, int row, int k, float v) {
  b[swzidx(row, k)] = v;
}
__device__ __forceinline__ float4 ldswz4f(const float* b, int row, int k) { // k%4==0
  return *(const float4*)(b + (row << 6) + ((((k >> 2) ^ ((row >> 2) & 7)) << 2)));
}
__device__ __forceinline__ void stswz4f(float* b, int row, int k, float4 v) {
  *(float4*)(b + (row << 6) + ((((k >> 2) ^ ((row >> 2) & 7)) << 2))) = v;
}

// ---- async global->LDS 16B (wave-uniform LDS base + lane*16; global per-lane)
__device__ __forceinline__ void gload_lds16(const float* g, float* l) {
  __builtin_amdgcn_global_load_lds(
      (const __attribute__((address_space(1))) unsigned int*)g,
      (__attribute__((address_space(3))) unsigned int*)l, 16, 0, 0);
}

// ---- fp32 -> bf16 hi/lo split (truncation; lo captures next 16 mantissa bits)
__device__ __forceinline__ void cvt_hilo(float4 p, float4 q, bf16x8& hi, bf16x8& lo) {
  float x[8] = {p.x, p.y, p.z, p.w, q.x, q.y, q.z, q.w};
#pragma unroll
  for (int j = 0; j < 8; ++j) {
    const unsigned u = __float_as_uint(x[j]);
    const float hf = __uint_as_float(u & 0xFFFF0000u);
    hi[j] = (short)(u >> 16);
    lo[j] = (short)(__float_as_uint(x[j] - hf) >> 16);
  }
}

// ---------------------------------------------------------------------------
// Gram kernel (MFMA): unchanged from R7/R8.
__global__ __launch_bounds__(512) void k_gram(const float* __restrict__ x1,
                                              const float* __restrict__ x2,
                                              float* __restrict__ gp,
                                              float* __restrict__ sp) {
  __shared__ __align__(16) float X1s[2][4096];
  __shared__ __align__(16) float X2s[2][4096];
  const int tid = threadIdx.x;
  const int b = blockIdx.x >> 7;
  const int chunk = blockIdx.x & 127;

  const int w = tid >> 6;          // wave 0..7
  const int grp = w >> 2;          // k-group
  const int wl = w & 3;            // wave-in-group -> G row-block
  const int l = tid & 63;
  const int lrow = l & 15;         // A row / B col within 16
  const int lkg = l >> 4;          // k-group-of-8 within frag
  const int arow = (wl << 4) + lrow;
  const size_t base = ((size_t)b << 22) + ((size_t)chunk << 9) + (grp << 8);

  f32x4 acc[4] = {};
  float s_own = 0.f;
  const int gtid = tid & 255;
  const int srow128 = gtid >> 1;
  const int sr = srow128 & 63;
  const float* sarr = (srow128 < 64) ? X1s[grp] : X2s[grp];
  const int shalf = (gtid & 1) << 3;

  for (int t = 0; t < 4; ++t) {
    __syncthreads();
#pragma unroll
    for (int q = 0; q < 4; ++q) {
      const int ck = (wl << 2) + q;
      const int c = (ck << 2) + lkg;
      const int kb = lrow;
      const size_t off = base + ((size_t)c << 16) + (t << 6) + ((kb ^ (c & 7)) << 2);
      gload_lds16(x1 + off, &X1s[grp][ck << 8]);
      gload_lds16(x2 + off, &X2s[grp][ck << 8]);
    }
    __syncthreads();

#pragma unroll
    for (int j = 0; j < 8; ++j) {
      const int kb2 = (shalf + j) ^ (sr & 7);
      const float4 v = *(const float4*)&sarr[(sr << 6) + (kb2 << 2)];
      s_own += v.x + v.y + v.z + v.w;
    }

#pragma unroll
    for (int ks = 0; ks < 2; ++ks) {
      const int kb0 = (ks << 3) + (lkg << 1);
      bf16x8 ahi, alo;
      {
        const float4 p = *(const float4*)&X1s[grp][(arow << 6) + ((kb0 ^ (arow & 7)) << 2)];
        const float4 q2 = *(const float4*)&X1s[grp][(arow << 6) + (((kb0 + 1) ^ (arow & 7)) << 2)];
        cvt_hilo(p, q2, ahi, alo);
      }
#pragma unroll
      for (int n = 0; n < 4; ++n) {
        const int brow = (n << 4) + lrow;
        const float4 p = *(const float4*)&X2s[grp][(brow << 6) + ((kb0 ^ (brow & 7)) << 2)];
        const float4 q2 = *(const float4*)&X2s[grp][(brow << 6) + (((kb0 + 1) ^ (brow & 7)) << 2)];
        bf16x8 bhi, blo;
        cvt_hilo(p, q2, bhi, blo);
        acc[n] = __builtin_amdgcn_mfma_f32_16x16x32_bf16(ahi, bhi, acc[n], 0, 0, 0);
        acc[n] = __builtin_amdgcn_mfma_f32_16x16x32_bf16(ahi, blo, acc[n], 0, 0, 0);
        acc[n] = __builtin_amdgcn_mfma_f32_16x16x32_bf16(alo, bhi, acc[n], 0, 0, 0);
      }
    }
  }

  __syncthreads();
  const float so = s_own + __shfl_xor(s_own, 1);
  float* exA = &X1s[0][0];
  float* exS = &X2s[0][0];
  if (grp == 1) {
#pragma unroll
    for (int n = 0; n < 4; ++n) {
      *(float4*)&exA[((n << 8) + (wl << 6) + l) << 2] =
          make_float4(acc[n][0], acc[n][1], acc[n][2], acc[n][3]);
    }
    if ((gtid & 1) == 0) exS[srow128] = so;
  }
  __syncthreads();
  if (grp == 0) {
#pragma unroll
    for (int n = 0; n < 4; ++n) {
      const float4 v = *(const float4*)&exA[((n << 8) + (wl << 6) + l) << 2];
      acc[n][0] += v.x; acc[n][1] += v.y; acc[n][2] += v.z; acc[n][3] += v.w;
    }
    if ((gtid & 1) == 0) sp[(blockIdx.x << 7) + srow128] = so + exS[srow128];
    float* g = gp + ((size_t)blockIdx.x << 12);
#pragma unroll
    for (int n = 0; n < 4; ++n) {
#pragma unroll
      for (int r = 0; r < 4; ++r) {
        g[(((wl << 4) + (lkg << 2) + r) << 6) + (n << 4) + lrow] = acc[n][r];
      }
    }
  }
}

// ---------------------------------------------------------------------------
// Reduce 128 partials per batch into final G and channel sums.
__global__ __launch_bounds__(256) void k_reduce(float* __restrict__ ws) {
  const int g = blockIdx.x;
  const int tid = threadIdx.x;
  if (g < 64) {
    const int idx = (g << 8) + tid;            // 0..16383
    const int b = idx >> 12, e = idx & 4095;
    const float* p = ws + GP_OFF + (((size_t)b << 7) << 12) + e;
    float a = 0.f;
#pragma unroll 8
    for (int k = 0; k < 128; ++k) a += p[(size_t)k << 12];
    ws[G_OFF + idx] = a;
  } else {
    const int b = g - 64;
    if (tid < 128) {
      const float* p = ws + SP_OFF + ((b << 7) << 7) + tid;
      float a = 0.f;
#pragma unroll 8
      for (int k = 0; k < 128; ++k) a += p[k << 7];
      if (tid < 64) ws[S1_OFF + (b << 6) + tid] = a;
      else          ws[S2_OFF + (b << 6) + (tid - 64)] = a;
    }
  }
}

// ---------------------------------------------------------------------------
// 64x64 fp32 matmul in swizzled LDS. D[c][d] = sum_k A[c][k] * (TRANSB ? B[d][k] : B[k][d])
template <bool TRANSB>
__device__ __forceinline__ void mm64(const float* __restrict__ A, const float* __restrict__ B,
                                     float* __restrict__ D, int tid) {
  const int c0 = (tid >> 4) << 2;
  const int d0 = (tid & 15) << 2;
  float acc[4][4] = {{0.f}};
#pragma unroll
  for (int kb = 0; kb < 64; kb += 4) {
    float4 a[4];
#pragma unroll
    for (int i = 0; i < 4; ++i) a[i] = ldswz4f(A, c0 + i, kb);
    if (TRANSB) {
#pragma unroll
      for (int j = 0; j < 4; ++j) {
        const float4 bj = ldswz4f(B, d0 + j, kb);
#pragma unroll
        for (int i = 0; i < 4; ++i) {
          acc[i][j] += a[i].x * bj.x + a[i].y * bj.y + a[i].z * bj.z + a[i].w * bj.w;
        }
      }
    } else {
#pragma unroll
      for (int r = 0; r < 4; ++r) {
        const float4 q = ldswz4f(B, kb + r, d0);
        const float br[4] = {q.x, q.y, q.z, q.w};
#pragma unroll
        for (int i = 0; i < 4; ++i) {
          const float av = (r == 0) ? a[i].x : (r == 1) ? a[i].y : (r == 2) ? a[i].z : a[i].w;
#pragma unroll
          for (int j = 0; j < 4; ++j) acc[i][j] += av * br[j];
        }
      }
    }
  }
#pragma unroll
  for (int i = 0; i < 4; ++i) {
    stswz4f(D, c0 + i, d0, make_float4(acc[i][0], acc[i][1], acc[i][2], acc[i][3]));
  }
}

// M = A @ B (non-trans); store row-major as bf16 hi/lo shorts (exact split).
__device__ __forceinline__ void mm64_store_hilo(const float* __restrict__ A,
                                                const float* __restrict__ B,
                                                unsigned short* __restrict__ MH,
                                                unsigned short* __restrict__ ML,
                                                int tid) {
  const int c0 = (tid >> 4) << 2;
  const int d0 = (tid & 15) << 2;
  float acc[4][4] = {{0.f}};
#pragma unroll
  for (int kb = 0; kb < 64; kb += 4) {
    float4 a[4];
#pragma unroll
    for (int i = 0; i < 4; ++i) a[i] = ldswz4f(A, c0 + i, kb);
#pragma unroll
    for (int r = 0; r < 4; ++r) {
      const float4 q = ldswz4f(B, kb + r, d0);
      const float br[4] = {q.x, q.y, q.z, q.w};
#pragma unroll
      for (int i = 0; i < 4; ++i) {
        const float av = (r == 0) ? a[i].x : (r == 1) ? a[i].y : (r == 2) ? a[i].z : a[i].w;
#pragma unroll
        for (int j = 0; j < 4; ++j) acc[i][j] += av * br[j];
      }
    }
  }
#pragma unroll
  for (int i = 0; i < 4; ++i) {
#pragma unroll
    for (int j = 0; j < 4; ++j) {
      const float v = acc[i][j];
      const unsigned u = __float_as_uint(v);
      const float hf = __uint_as_float(u & 0xFFFF0000u);
      const int idx = ((c0 + i) << 6) + d0 + j;
      MH[idx] = (unsigned short)(u >> 16);
      ML[idx] = (unsigned short)(__float_as_uint(v - hf) >> 16);
    }
  }
}

__device__ __forceinline__ void load64x64(const float* __restrict__ g, float* __restrict__ lds, int tid) {
#pragma unroll
  for (int r = 0; r < 4; ++r) {
    const int idx = (r << 8) + tid;
    const int row = idx >> 4;
    const int b4 = (idx & 15) << 2;
    stswz4f(lds, row, b4, *(const float4*)(g + (row << 6) + b4));
  }
}

// ---------------------------------------------------------------------------
// Middle kernel: 8 blocks = 4 batches x 2 sides. Builds logits from G/s,
// softmax, then M (bf16 hi/lo into GP alias) and c vectors into ws.
__global__ __launch_bounds__(256) void k_mid(
    const float* __restrict__ wq1, const float* __restrict__ bq1,
    const float* __restrict__ wk2, const float* __restrict__ bk2,
    const float* __restrict__ wv2, const float* __restrict__ bv2,
    const float* __restrict__ wo1, const float* __restrict__ bo1,
    const float* __restrict__ wq2, const float* __restrict__ bq2,
    const float* __restrict__ wk1, const float* __restrict__ bk1,
    const float* __restrict__ wv1, const float* __restrict__ bv1,
    const float* __restrict__ wo2, const float* __restrict__ bo2,
    float* __restrict__ ws) {
  __shared__ __align__(16) float LA[4096];
  __shared__ __align__(16) float LB[4096];
  __shared__ __align__(16) float LC[4096];
  __shared__ __align__(16) float LD[4096];
  __shared__ float vsq[64], vsk[64], vaq[64], vkk[64], vcv[64];

  const int tid = threadIdx.x;
  const int b = blockIdx.x >> 1;
  const int side = blockIdx.x & 1;

  const float *Wq, *Bq, *Wk, *Bk, *Wv, *Bv, *Wo, *Bo, *sqp, *skp;
  if (side == 0) {
    Wq = wq1; Bq = bq1; Wk = wk2; Bk = bk2; Wv = wv2; Bv = bv2; Wo = wo1; Bo = bo1;
    sqp = ws + S1_OFF + (b << 6); skp = ws + S2_OFF + (b << 6);
  } else {
    Wq = wq2; Bq = bq2; Wk = wk1; Bk = bk1; Wv = wv1; Bv = bv1; Wo = wo2; Bo = bo2;
    sqp = ws + S2_OFF + (b << 6); skp = ws + S1_OFF + (b << 6);
  }
  const int job = (side << 2) + b;
  unsigned short* MH = (unsigned short*)(ws + GP_OFF) + (job << 12);
  unsigned short* ML = (unsigned short*)(ws + GP_OFF) + (8 << 12) + (job << 12);
  float* Cv = ws + CV_OFF + (job << 6);
  const float* G = ws + G_OFF + (b << 12);

  if (tid < 64) { vsq[tid] = sqp[tid]; vsk[tid] = skp[tid]; }
  load64x64(G, LA, tid);
  load64x64(Wq, LB, tid);
  __syncthreads();
  if (tid < 64) {  // aq = Wq @ sq
    float a = 0.f;
    for (int k = 0; k < 64; ++k) a += ldswz1(LB, tid, k) * vsq[k];
    vaq[tid] = a;
  }
  // T = Wq @ G (side0)  or  Wq @ G^T (side1)
  if (side == 0) mm64<false>(LB, LA, LC, tid);
  else           mm64<true >(LB, LA, LC, tid);
  __syncthreads();
  load64x64(Wk, LB, tid);
  __syncthreads();
  if (tid < 64) {  // kk = Wk @ sk
    float a = 0.f;
    for (int k = 0; k < 64; ++k) a += ldswz1(LB, tid, k) * vsk[k];
    vkk[tid] = a;
  }
  mm64<true>(LC, LB, LD, tid);  // S = T @ Wk^T
  __syncthreads();
  // assemble logits: S = scale*(S + aq[c]*bk[d] + bq[c]*(kk[d] + N*bk[d]))
#pragma unroll
  for (int t = 0; t < 16; ++t) {
    const int idx = (t << 8) + tid;
    const int c = idx >> 6, d = idx & 63;
    const float bkv = Bk[d], bqv = Bq[c];
    float v = ldswz1(LD, c, d);
    v = SCALE * (v + vaq[c] * bkv + bqv * (vkk[d] + 65536.f * bkv));
    stswz1(LD, c, d, v);
  }
  __syncthreads();
  {  // row softmax, 4 lanes per row
    const int row = tid >> 2, q = tid & 3;
    float ev[16];
    float mx = -3.4e38f;
#pragma unroll
    for (int t = 0; t < 16; ++t) { ev[t] = ldswz1(LD, row, q + (t << 2)); mx = fmaxf(mx, ev[t]); }
    mx = fmaxf(mx, __shfl_xor(mx, 1));
    mx = fmaxf(mx, __shfl_xor(mx, 2));
    float sm = 0.f;
#pragma unroll
    for (int t = 0; t < 16; ++t) { ev[t] = __expf(ev[t] - mx); sm += ev[t]; }
    sm += __shfl_xor(sm, 1);
    sm += __shfl_xor(sm, 2);
    const float inv = 1.f / sm;
#pragma unroll
    for (int t = 0; t < 16; ++t) stswz1(LD, row, q + (t << 2), ev[t] * inv);
  }
  __syncthreads();
  if (tid < 64) {  // cv = attn @ bv
    float a = 0.f;
    for (int d = 0; d < 64; ++d) a += ldswz1(LD, tid, d) * Bv[d];
    vcv[tid] = a;
  }
  load64x64(Wv, LB, tid);
  __syncthreads();
  mm64<false>(LD, LB, LC, tid);  // U = attn @ Wv
  __syncthreads();
  load64x64(Wo, LB, tid);
  __syncthreads();
  mm64_store_hilo(LB, LC, MH, ML, tid);  // M = Wo @ U -> bf16 hi/lo
  if (tid < 64) {                // c = Wo @ cv + bo
    float a = 0.f;
    for (int c = 0; c < 64; ++c) a += ldswz1(LB, tid, c) * vcv[c];
    Cv[tid] = a + Bo[tid];
  }
}

// ---------------------------------------------------------------------------
// Apply kernel (R9, MFMA): 512 blocks x 512 thr; block owns 512 px of one
// batch as 8 half-tiles of 64 px, double-buffered (2x32KB, XOR-swizzled
// 16B blocks within rows). Wave w: side=w>>2, px16=(w&3)*16. Per half:
// acc[4 octiles] (16 f32), X-frag = 8 ds_read_b32 + bf16 truncate per
// k-step, 2 mfma per octile per k-step ((Mh+Ml)*Xh). M-frags + bias live
// in VGPRs across all halves. R8 pipeline skeleton (vmcnt(16), s_barrier).
__global__ __launch_bounds__(512) void k_apply(const float* __restrict__ x1,
                                               const float* __restrict__ x2,
                                               const float* __restrict__ ws,
                                               float* __restrict__ out) {
  __shared__ __align__(16) float buf[2][8192];  // [dbuf][side*4096 + ch*64 + px(swz)]
  const int tid = threadIdx.x;
  const int b = blockIdx.x >> 7;
  const int px_blk = (blockIdx.x & 127) << 9;   // 512 px per block
  const size_t bb = (size_t)b << 22;

  const int w = tid >> 6;
  const int l = tid & 63;
  const int wu = __builtin_amdgcn_readfirstlane(w);
  const int side = wu >> 2;
  const int p16 = (wu & 3) << 4;                // px16 base within 64-px half
  const int job = (side << 2) + b;
  const int lr = l & 15;                        // M-row / px within 16
  const int lg = l >> 4;                        // k-group / D-row group
  const int px = p16 + lr;                      // px within 64-px half
  const int pxb = px >> 2;                      // 16B block of px
  const int pxi = px & 3;

  // M fragments (resident): 4 octiles x 2 ksteps x {hi,lo}
  const unsigned short* MH = (const unsigned short*)(ws + GP_OFF) + (job << 12);
  const unsigned short* ML = (const unsigned short*)(ws + GP_OFF) + (8 << 12) + (job << 12);
  bf16x8 mh[4][2], ml[4][2];
#pragma unroll
  for (int n = 0; n < 4; ++n) {
#pragma unroll
    for (int ks = 0; ks < 2; ++ks) {
      const int idx = (((n << 4) + lr) << 6) + (ks << 5) + (lg << 3);
      mh[n][ks] = *(const bf16x8*)&MH[idx];
      ml[n][ks] = *(const bf16x8*)&ML[idx];
    }
  }
  // bias for this thread's 16 output elements: o = n*16 + lg*4 + r
  const float* Cvp = ws + CV_OFF + (job << 6);
  float cvr[16];
#pragma unroll
  for (int n = 0; n < 4; ++n)
#pragma unroll
    for (int r = 0; r < 4; ++r) cvr[(n << 2) + r] = Cvp[(n << 4) + (lg << 2) + r];

  // stage half h into buf[h&1]: 32 chunks of 1KB (4 ch-rows x 64px);
  // chunk>>4 = side; LDS block kb=(l&15) holds global px-block kb^(c&7).
#define STAGE_HALF(h)                                                         \
  {                                                                           \
    _Pragma("unroll") for (int q = 0; q < 4; ++q) {                           \
      const int ckk = (w << 2) + q;                                           \
      const int c = ((ckk & 15) << 2) + (l >> 4);                             \
      const size_t off = bb + ((size_t)c << 16) + px_blk + ((h) << 6) +       \
                         (((l & 15) ^ (c & 7)) << 2);                         \
      gload_lds16(((ckk >> 4) ? x2 : x1) + off, &buf[(h) & 1][ckk << 8]);     \
    }                                                                         \
  }

  STAGE_HALF(0);

#pragma unroll 1
  for (int h = 0; h < 8; ++h) {
    if (h == 0) {
      asm volatile("s_waitcnt vmcnt(0)" ::: "memory");
    } else {
      // outstanding: 4 stage(h) loads (oldest) + 16 stores from half h-1
      asm volatile("s_waitcnt vmcnt(16)" ::: "memory");
    }
    __builtin_amdgcn_s_barrier();
    __builtin_amdgcn_sched_barrier(0);
    if (h + 1 < 8) STAGE_HALF(h + 1);
    __builtin_amdgcn_sched_barrier(0);  // pin stage issue before compute

    const float* bufc = buf[h & 1];
    const float* bo = bufc + ((side ^ 1) << 12);  // cross input
    const float* bw = bufc + (side << 12);        // own side (residual)

    f32x4 acc[4];
#pragma unroll
    for (int n = 0; n < 4; ++n) {
#pragma unroll
      for (int r = 0; r < 4; ++r) {
        const int o = (n << 4) + (lg << 2) + r;
        acc[n][r] = cvr[(n << 2) + r] + bw[(o << 6) + ((pxb ^ (o & 7)) << 2) + pxi];
      }
    }

#pragma unroll
    for (int ks = 0; ks < 2; ++ks) {
      bf16x8 xh;
#pragma unroll
      for (int e = 0; e < 8; ++e) {
        const int rr = (ks << 5) + (lg << 3) + e;
        const float v = bo[(rr << 6) + ((pxb ^ (rr & 7)) << 2) + pxi];
        xh[e] = (short)(__float_as_uint(v) >> 16);
      }
#pragma unroll
      for (int n = 0; n < 4; ++n) {
        acc[n] = __builtin_amdgcn_mfma_f32_16x16x32_bf16(mh[n][ks], xh, acc[n], 0, 0, 0);
        acc[n] = __builtin_amdgcn_mfma_f32_16x16x32_bf16(ml[n][ks], xh, acc[n], 0, 0, 0);
      }
    }

    const size_t po = ((size_t)side << 24) + bb + px_blk + (h << 6) + px;
#pragma unroll
    for (int n = 0; n < 4; ++n) {
#pragma unroll
      for (int r = 0; r < 4; ++r) {
        const int o = (n << 4) + (lg << 2) + r;
        out[po + ((size_t)o << 16)] = acc[n][r];
      }
    }
  }
#undef STAGE_HALF
}

// ---------------------------------------------------------------------------
extern "C" void kernel_launch(void* const* d_in, const int* in_sizes, int n_in,
                              void* d_out, int out_size, void* d_ws, size_t ws_size,
                              hipStream_t stream) {
  const float* x1 = (const float*)d_in[0];
  const float* x2 = (const float*)d_in[1];
  float* ws = (float*)d_ws;
  float* out = (float*)d_out;

  k_gram<<<NBLK_GRAM, 512, 0, stream>>>(x1, x2, ws + GP_OFF, ws + SP_OFF);
  k_reduce<<<68, 256, 0, stream>>>(ws);
  k_mid<<<8, 256, 0, stream>>>(
      (const float*)d_in[2],  (const float*)d_in[3],   // w_q1, b_q1
      (const float*)d_in[4],  (const float*)d_in[5],   // w_k2, b_k2
      (const float*)d_in[6],  (const float*)d_in[7],   // w_v2, b_v2
      (const float*)d_in[14], (const float*)d_in[15],  // w_o1, b_o1
      (const float*)d_in[8],  (const float*)d_in[9],   // w_q2, b_q2
      (const float*)d_in[10], (const float*)d_in[11],  // w_k1, b_k1
      (const float*)d_in[12], (const float*)d_in[13],  // w_v1, b_v1
      (const float*)d_in[16], (const float*)d_in[17],  // w_o2, b_o2
      ws);
  k_apply<<<512, 512, 0, stream>>>(x1, x2, ws, out);
}

// Round 10
// 99.635 us; speedup vs baseline: 1.4495x; 1.0110x over previous
//
#include <hip/hip_runtime.h>

// ---------------------------------------------------------------------------
// SymmetricCrossAttention, B=4, C=64, H=W=256, HEADS=1.
// out1 = M1 X2 + c1 + X1, out2 = M2 X1 + c2 + X2 with M,c derived from
// G12 = X1 X2^T (64x64 per batch) + channel sums (k_gram/k_reduce/k_mid).
// R10: k_gram pipelined like R9's k_apply: 32-px tiles (8/group), per-group
//      2x16KB double buffer (64KB total, 2 blocks/CU), per tile
//      {wait vmcnt(0); s_barrier; STAGE(t+1); compute(t)} -- stage overlaps
//      compute. Was: serial stage->drain->compute, ~38us vs 21us HBM floor.
//      k_apply (MFMA, R9) / k_reduce / k_mid unchanged.
// ---------------------------------------------------------------------------

#define NPIX 65536
#define SCALE 0.125f
#define NBLK_GRAM 512      // 4 batches * 128 chunks (512 px each)

// workspace float offsets (unchanged since R2 -- ws_size proven >= 8.85MB)
#define GP_OFF  0                      // 512 * 4096 partial Grams (dead after
                                       // k_reduce; k_mid aliases MH/ML here)
#define SP_OFF  2097152                // 512 * 128 partial channel sums (s1|s2)
#define G_OFF   2162688                // 4 * 4096
#define S1_OFF  2179072                // 4 * 64
#define S2_OFF  2179328                // 4 * 64
#define MT_OFF  2179584                // (unused)
#define CV_OFF  2212352                // 2*4*64
#define WS_FLOATS 2212864              // ~8.85 MB

typedef __attribute__((ext_vector_type(8))) short bf16x8;  // 4 VGPR A/B frag
typedef __attribute__((ext_vector_type(4))) float f32x4;   // 16x16 C/D frag

// ---- XOR-swizzled 64x64 fp32 LDS tile helpers (16B-block index ^ (row>>2)&7)
__device__ __forceinline__ int swzidx(int row, int k) {
  return (row << 6) + ((((k >> 2) ^ ((row >> 2) & 7)) << 2) | (k & 3));
}
__device__ __forceinline__ float ldswz1(const float* b, int row, int k) {
  return b[swzidx(row, k)];
}
__device__ __forceinline__ void stswz1(float* b, int row, int k, float v) {
  b[swzidx(row, k)] = v;
}
__device__ __forceinline__ float4 ldswz4f(const float* b, int row, int k) { // k%4==0
  return *(const float4*)(b + (row << 6) + ((((k >> 2) ^ ((row >> 2) & 7)) << 2)));
}
__device__ __forceinline__ void stswz4f(float* b, int row, int k, float4 v) {
  *(float4*)(b + (row << 6) + ((((k >> 2) ^ ((row >> 2) & 7)) << 2))) = v;
}

// ---- async global->LDS 16B (wave-uniform LDS base + lane*16; global per-lane)
__device__ __forceinline__ void gload_lds16(const float* g, float* l) {
  __builtin_amdgcn_global_load_lds(
      (const __attribute__((address_space(1))) unsigned int*)g,
      (__attribute__((address_space(3))) unsigned int*)l, 16, 0, 0);
}

// ---- fp32 -> bf16 hi/lo split (truncation; lo captures next 16 mantissa bits)
__device__ __forceinline__ void cvt_hilo(float4 p, float4 q, bf16x8& hi, bf16x8& lo) {
  float x[8] = {p.x, p.y, p.z, p.w, q.x, q.y, q.z, q.w};
#pragma unroll
  for (int j = 0; j < 8; ++j) {
    const unsigned u = __float_as_uint(x[j]);
    const float hf = __uint_as_float(u & 0xFFFF0000u);
    hi[j] = (short)(u >> 16);
    lo[j] = (short)(__float_as_uint(x[j] - hf) >> 16);
  }
}

// ---------------------------------------------------------------------------
// Gram kernel (MFMA, pipelined): per batch, G12 = X1 X2^T + channel sums.
// 512 blocks x 512 thr = 2 k-groups x 4 waves. Group g owns px half
// [g*256, +256) as 8 tiles of 32 px, double-buffered (2x16KB per group).
// LDS region (grp, dbuf, arr) = lds + ((grp<<2)+(d<<1)+a)*2048 floats.
// Tile rows: 64 ch x 8 px-blocks(16B), block pb holds global block pb^(c&7).
__global__ __launch_bounds__(512) void k_gram(const float* __restrict__ x1,
                                              const float* __restrict__ x2,
                                              float* __restrict__ gp,
                                              float* __restrict__ sp) {
  __shared__ __align__(16) float lds[16384];
  const int tid = threadIdx.x;
  const int b = blockIdx.x >> 7;
  const int chunk = blockIdx.x & 127;

  const int w = tid >> 6;          // wave 0..7
  const int grp = w >> 2;          // k-group
  const int wl = w & 3;            // wave-in-group -> G row-block
  const int l = tid & 63;
  const int lrow = l & 15;         // A row / B col within 16
  const int lkg = l >> 4;          // k-group-of-8 within frag (0..3)
  const int arow = (wl << 4) + lrow;
  const size_t base = ((size_t)b << 22) + ((size_t)chunk << 9) + (grp << 8);

  f32x4 acc[4] = {};
  float s_own = 0.f;
  const int gtid = tid & 255;
  const int srow128 = gtid >> 1;   // 0..127
  const int sr = srow128 & 63;
  const int sa = srow128 >> 6;     // 0 -> X1, 1 -> X2
  const int sh = (gtid & 1) << 2;  // px-block half: 0..3 or 4..7

  // stage tile t of this group into buffer (t&1): 16 chunks of 1KB
  // (8 rows x 8 blocks each); wave wl: X1 chunks {2wl,2wl+1}, X2 same.
#define STAGE_T(t)                                                            \
  {                                                                           \
    _Pragma("unroll") for (int q = 0; q < 4; ++q) {                           \
      const int a = q >> 1;                                                   \
      const int ck = (wl << 1) | (q & 1);                                     \
      const int r = (ck << 3) + (l >> 3);                                     \
      const size_t off = base + ((t) << 5) + ((size_t)r << 16) +              \
                         (((l & 7) ^ (r & 7)) << 2);                          \
      gload_lds16((a ? x2 : x1) + off,                                        \
                  &lds[((grp << 2) + (((t) & 1) << 1) + a) << 11] + (ck << 8)); \
    }                                                                         \
  }

  STAGE_T(0);

#pragma unroll 1
  for (int t = 0; t < 8; ++t) {
    asm volatile("s_waitcnt vmcnt(0)" ::: "memory");  // own stage(t) done
    __builtin_amdgcn_s_barrier();                     // all waves' stage(t) done
    __builtin_amdgcn_sched_barrier(0);
    if (t + 1 < 8) STAGE_T(t + 1);                    // overlaps compute(t)
    __builtin_amdgcn_sched_barrier(0);

    const int d = t & 1;
    const float* R1 = &lds[((grp << 2) + (d << 1)) << 11];
    const float* R2 = R1 + 2048;
    const float* sarr = &lds[((grp << 2) + (d << 1) + sa) << 11];

    // channel sums (4 of 8 blocks per thread; 2 threads/row)
#pragma unroll
    for (int j = 0; j < 4; ++j) {
      const int kb2 = (sh + j) ^ (sr & 7);
      const float4 v = *(const float4*)&sarr[(sr << 5) + (kb2 << 2)];
      s_own += v.x + v.y + v.z + v.w;
    }

    // MFMA: one K=32 step per tile
    const int kb0 = lkg << 1;
    bf16x8 ahi, alo;
    {
      const float4 p = *(const float4*)&R1[(arow << 5) + ((kb0 ^ (arow & 7)) << 2)];
      const float4 q2 = *(const float4*)&R1[(arow << 5) + (((kb0 + 1) ^ (arow & 7)) << 2)];
      cvt_hilo(p, q2, ahi, alo);
    }
#pragma unroll
    for (int n = 0; n < 4; ++n) {
      const int brow = (n << 4) + lrow;
      const float4 p = *(const float4*)&R2[(brow << 5) + ((kb0 ^ (brow & 7)) << 2)];
      const float4 q2 = *(const float4*)&R2[(brow << 5) + (((kb0 + 1) ^ (brow & 7)) << 2)];
      bf16x8 bhi, blo;
      cvt_hilo(p, q2, bhi, blo);
      acc[n] = __builtin_amdgcn_mfma_f32_16x16x32_bf16(ahi, bhi, acc[n], 0, 0, 0);
      acc[n] = __builtin_amdgcn_mfma_f32_16x16x32_bf16(ahi, blo, acc[n], 0, 0, 0);
      acc[n] = __builtin_amdgcn_mfma_f32_16x16x32_bf16(alo, bhi, acc[n], 0, 0, 0);
    }
  }
#undef STAGE_T

  // ---- cross-group combine (tiles all consumed; reuse LDS front) ----
  __syncthreads();
  const float so = s_own + __shfl_xor(s_own, 1);  // pair-reduce row halves
  float* exA = lds;                               // 4096 floats (grp0/d0 regions)
  float* exS = lds + 4096;                        // 128 floats
  if (grp == 1) {
#pragma unroll
    for (int n = 0; n < 4; ++n) {
      *(float4*)&exA[((n << 8) + (wl << 6) + l) << 2] =
          make_float4(acc[n][0], acc[n][1], acc[n][2], acc[n][3]);
    }
    if ((gtid & 1) == 0) exS[srow128] = so;
  }
  __syncthreads();
  if (grp == 0) {
#pragma unroll
    for (int n = 0; n < 4; ++n) {
      const float4 v = *(const float4*)&exA[((n << 8) + (wl << 6) + l) << 2];
      acc[n][0] += v.x; acc[n][1] += v.y; acc[n][2] += v.z; acc[n][3] += v.w;
    }
    if ((gtid & 1) == 0) sp[(blockIdx.x << 7) + srow128] = so + exS[srow128];
    // G partial: C/D layout col=lane&15, row=(lane>>4)*4+reg (m89-verified)
    float* g = gp + ((size_t)blockIdx.x << 12);
#pragma unroll
    for (int n = 0; n < 4; ++n) {
#pragma unroll
      for (int r = 0; r < 4; ++r) {
        g[(((wl << 4) + (lkg << 2) + r) << 6) + (n << 4) + lrow] = acc[n][r];
      }
    }
  }
}

// ---------------------------------------------------------------------------
// Reduce 128 partials per batch into final G and channel sums.
__global__ __launch_bounds__(256) void k_reduce(float* __restrict__ ws) {
  const int g = blockIdx.x;
  const int tid = threadIdx.x;
  if (g < 64) {
    const int idx = (g << 8) + tid;            // 0..16383
    const int b = idx >> 12, e = idx & 4095;
    const float* p = ws + GP_OFF + (((size_t)b << 7) << 12) + e;
    float a = 0.f;
#pragma unroll 8
    for (int k = 0; k < 128; ++k) a += p[(size_t)k << 12];
    ws[G_OFF + idx] = a;
  } else {
    const int b = g - 64;
    if (tid < 128) {
      const float* p = ws + SP_OFF + ((b << 7) << 7) + tid;
      float a = 0.f;
#pragma unroll 8
      for (int k = 0; k < 128; ++k) a += p[k << 7];
      if (tid < 64) ws[S1_OFF + (b << 6) + tid] = a;
      else          ws[S2_OFF + (b << 6) + (tid - 64)] = a;
    }
  }
}

// ---------------------------------------------------------------------------
// 64x64 fp32 matmul in swizzled LDS. D[c][d] = sum_k A[c][k] * (TRANSB ? B[d][k] : B[k][d])
template <bool TRANSB>
__device__ __forceinline__ void mm64(const float* __restrict__ A, const float* __restrict__ B,
                                     float* __restrict__ D, int tid) {
  const int c0 = (tid >> 4) << 2;
  const int d0 = (tid & 15) << 2;
  float acc[4][4] = {{0.f}};
#pragma unroll
  for (int kb = 0; kb < 64; kb += 4) {
    float4 a[4];
#pragma unroll
    for (int i = 0; i < 4; ++i) a[i] = ldswz4f(A, c0 + i, kb);
    if (TRANSB) {
#pragma unroll
      for (int j = 0; j < 4; ++j) {
        const float4 bj = ldswz4f(B, d0 + j, kb);
#pragma unroll
        for (int i = 0; i < 4; ++i) {
          acc[i][j] += a[i].x * bj.x + a[i].y * bj.y + a[i].z * bj.z + a[i].w * bj.w;
        }
      }
    } else {
#pragma unroll
      for (int r = 0; r < 4; ++r) {
        const float4 q = ldswz4f(B, kb + r, d0);
        const float br[4] = {q.x, q.y, q.z, q.w};
#pragma unroll
        for (int i = 0; i < 4; ++i) {
          const float av = (r == 0) ? a[i].x : (r == 1) ? a[i].y : (r == 2) ? a[i].z : a[i].w;
#pragma unroll
          for (int j = 0; j < 4; ++j) acc[i][j] += av * br[j];
        }
      }
    }
  }
#pragma unroll
  for (int i = 0; i < 4; ++i) {
    stswz4f(D, c0 + i, d0, make_float4(acc[i][0], acc[i][1], acc[i][2], acc[i][3]));
  }
}

// M = A @ B (non-trans); store row-major as bf16 hi/lo shorts (exact split).
__device__ __forceinline__ void mm64_store_hilo(const float* __restrict__ A,
                                                const float* __restrict__ B,
                                                unsigned short* __restrict__ MH,
                                                unsigned short* __restrict__ ML,
                                                int tid) {
  const int c0 = (tid >> 4) << 2;
  const int d0 = (tid & 15) << 2;
  float acc[4][4] = {{0.f}};
#pragma unroll
  for (int kb = 0; kb < 64; kb += 4) {
    float4 a[4];
#pragma unroll
    for (int i = 0; i < 4; ++i) a[i] = ldswz4f(A, c0 + i, kb);
#pragma unroll
    for (int r = 0; r < 4; ++r) {
      const float4 q = ldswz4f(B, kb + r, d0);
      const float br[4] = {q.x, q.y, q.z, q.w};
#pragma unroll
      for (int i = 0; i < 4; ++i) {
        const float av = (r == 0) ? a[i].x : (r == 1) ? a[i].y : (r == 2) ? a[i].z : a[i].w;
#pragma unroll
        for (int j = 0; j < 4; ++j) acc[i][j] += av * br[j];
      }
    }
  }
#pragma unroll
  for (int i = 0; i < 4; ++i) {
#pragma unroll
    for (int j = 0; j < 4; ++j) {
      const float v = acc[i][j];
      const unsigned u = __float_as_uint(v);
      const float hf = __uint_as_float(u & 0xFFFF0000u);
      const int idx = ((c0 + i) << 6) + d0 + j;
      MH[idx] = (unsigned short)(u >> 16);
      ML[idx] = (unsigned short)(__float_as_uint(v - hf) >> 16);
    }
  }
}

__device__ __forceinline__ void load64x64(const float* __restrict__ g, float* __restrict__ lds, int tid) {
#pragma unroll
  for (int r = 0; r < 4; ++r) {
    const int idx = (r << 8) + tid;
    const int row = idx >> 4;
    const int b4 = (idx & 15) << 2;
    stswz4f(lds, row, b4, *(const float4*)(g + (row << 6) + b4));
  }
}

// ---------------------------------------------------------------------------
// Middle kernel: 8 blocks = 4 batches x 2 sides. Builds logits from G/s,
// softmax, then M (bf16 hi/lo into GP alias) and c vectors into ws.
__global__ __launch_bounds__(256) void k_mid(
    const float* __restrict__ wq1, const float* __restrict__ bq1,
    const float* __restrict__ wk2, const float* __restrict__ bk2,
    const float* __restrict__ wv2, const float* __restrict__ bv2,
    const float* __restrict__ wo1, const float* __restrict__ bo1,
    const float* __restrict__ wq2, const float* __restrict__ bq2,
    const float* __restrict__ wk1, const float* __restrict__ bk1,
    const float* __restrict__ wv1, const float* __restrict__ bv1,
    const float* __restrict__ wo2, const float* __restrict__ bo2,
    float* __restrict__ ws) {
  __shared__ __align__(16) float LA[4096];
  __shared__ __align__(16) float LB[4096];
  __shared__ __align__(16) float LC[4096];
  __shared__ __align__(16) float LD[4096];
  __shared__ float vsq[64], vsk[64], vaq[64], vkk[64], vcv[64];

  const int tid = threadIdx.x;
  const int b = blockIdx.x >> 1;
  const int side = blockIdx.x & 1;

  const float *Wq, *Bq, *Wk, *Bk, *Wv, *Bv, *Wo, *Bo, *sqp, *skp;
  if (side == 0) {
    Wq = wq1; Bq = bq1; Wk = wk2; Bk = bk2; Wv = wv2; Bv = bv2; Wo = wo1; Bo = bo1;
    sqp = ws + S1_OFF + (b << 6); skp = ws + S2_OFF + (b << 6);
  } else {
    Wq = wq2; Bq = bq2; Wk = wk1; Bk = bk1; Wv = wv1; Bv = bv1; Wo = wo2; Bo = bo2;
    sqp = ws + S2_OFF + (b << 6); skp = ws + S1_OFF + (b << 6);
  }
  const int job = (side << 2) + b;
  unsigned short* MH = (unsigned short*)(ws + GP_OFF) + (job << 12);
  unsigned short* ML = (unsigned short*)(ws + GP_OFF) + (8 << 12) + (job << 12);
  float* Cv = ws + CV_OFF + (job << 6);
  const float* G = ws + G_OFF + (b << 12);

  if (tid < 64) { vsq[tid] = sqp[tid]; vsk[tid] = skp[tid]; }
  load64x64(G, LA, tid);
  load64x64(Wq, LB, tid);
  __syncthreads();
  if (tid < 64) {  // aq = Wq @ sq
    float a = 0.f;
    for (int k = 0; k < 64; ++k) a += ldswz1(LB, tid, k) * vsq[k];
    vaq[tid] = a;
  }
  // T = Wq @ G (side0)  or  Wq @ G^T (side1)
  if (side == 0) mm64<false>(LB, LA, LC, tid);
  else           mm64<true >(LB, LA, LC, tid);
  __syncthreads();
  load64x64(Wk, LB, tid);
  __syncthreads();
  if (tid < 64) {  // kk = Wk @ sk
    float a = 0.f;
    for (int k = 0; k < 64; ++k) a += ldswz1(LB, tid, k) * vsk[k];
    vkk[tid] = a;
  }
  mm64<true>(LC, LB, LD, tid);  // S = T @ Wk^T
  __syncthreads();
  // assemble logits: S = scale*(S + aq[c]*bk[d] + bq[c]*(kk[d] + N*bk[d]))
#pragma unroll
  for (int t = 0; t < 16; ++t) {
    const int idx = (t << 8) + tid;
    const int c = idx >> 6, d = idx & 63;
    const float bkv = Bk[d], bqv = Bq[c];
    float v = ldswz1(LD, c, d);
    v = SCALE * (v + vaq[c] * bkv + bqv * (vkk[d] + 65536.f * bkv));
    stswz1(LD, c, d, v);
  }
  __syncthreads();
  {  // row softmax, 4 lanes per row
    const int row = tid >> 2, q = tid & 3;
    float ev[16];
    float mx = -3.4e38f;
#pragma unroll
    for (int t = 0; t < 16; ++t) { ev[t] = ldswz1(LD, row, q + (t << 2)); mx = fmaxf(mx, ev[t]); }
    mx = fmaxf(mx, __shfl_xor(mx, 1));
    mx = fmaxf(mx, __shfl_xor(mx, 2));
    float sm = 0.f;
#pragma unroll
    for (int t = 0; t < 16; ++t) { ev[t] = __expf(ev[t] - mx); sm += ev[t]; }
    sm += __shfl_xor(sm, 1);
    sm += __shfl_xor(sm, 2);
    const float inv = 1.f / sm;
#pragma unroll
    for (int t = 0; t < 16; ++t) stswz1(LD, row, q + (t << 2), ev[t] * inv);
  }
  __syncthreads();
  if (tid < 64) {  // cv = attn @ bv
    float a = 0.f;
    for (int d = 0; d < 64; ++d) a += ldswz1(LD, tid, d) * Bv[d];
    vcv[tid] = a;
  }
  load64x64(Wv, LB, tid);
  __syncthreads();
  mm64<false>(LD, LB, LC, tid);  // U = attn @ Wv
  __syncthreads();
  load64x64(Wo, LB, tid);
  __syncthreads();
  mm64_store_hilo(LB, LC, MH, ML, tid);  // M = Wo @ U -> bf16 hi/lo
  if (tid < 64) {                // c = Wo @ cv + bo
    float a = 0.f;
    for (int c = 0; c < 64; ++c) a += ldswz1(LB, tid, c) * vcv[c];
    Cv[tid] = a + Bo[tid];
  }
}

// ---------------------------------------------------------------------------
// Apply kernel (MFMA, unchanged from R9): 512 blocks x 512 thr; 8 half-tiles
// of 64 px, double-buffered; M-frags resident in VGPRs; 2 mfma/octile/kstep.
__global__ __launch_bounds__(512) void k_apply(const float* __restrict__ x1,
                                               const float* __restrict__ x2,
                                               const float* __restrict__ ws,
                                               float* __restrict__ out) {
  __shared__ __align__(16) float buf[2][8192];  // [dbuf][side*4096 + ch*64 + px(swz)]
  const int tid = threadIdx.x;
  const int b = blockIdx.x >> 7;
  const int px_blk = (blockIdx.x & 127) << 9;   // 512 px per block
  const size_t bb = (size_t)b << 22;

  const int w = tid >> 6;
  const int l = tid & 63;
  const int wu = __builtin_amdgcn_readfirstlane(w);
  const int side = wu >> 2;
  const int p16 = (wu & 3) << 4;                // px16 base within 64-px half
  const int job = (side << 2) + b;
  const int lr = l & 15;                        // M-row / px within 16
  const int lg = l >> 4;                        // k-group / D-row group
  const int px = p16 + lr;                      // px within 64-px half
  const int pxb = px >> 2;                      // 16B block of px
  const int pxi = px & 3;

  // M fragments (resident): 4 octiles x 2 ksteps x {hi,lo}
  const unsigned short* MH = (const unsigned short*)(ws + GP_OFF) + (job << 12);
  const unsigned short* ML = (const unsigned short*)(ws + GP_OFF) + (8 << 12) + (job << 12);
  bf16x8 mh[4][2], ml[4][2];
#pragma unroll
  for (int n = 0; n < 4; ++n) {
#pragma unroll
    for (int ks = 0; ks < 2; ++ks) {
      const int idx = (((n << 4) + lr) << 6) + (ks << 5) + (lg << 3);
      mh[n][ks] = *(const bf16x8*)&MH[idx];
      ml[n][ks] = *(const bf16x8*)&ML[idx];
    }
  }
  // bias for this thread's 16 output elements: o = n*16 + lg*4 + r
  const float* Cvp = ws + CV_OFF + (job << 6);
  float cvr[16];
#pragma unroll
  for (int n = 0; n < 4; ++n)
#pragma unroll
    for (int r = 0; r < 4; ++r) cvr[(n << 2) + r] = Cvp[(n << 4) + (lg << 2) + r];

  // stage half h into buf[h&1]: 32 chunks of 1KB (4 ch-rows x 64px);
  // chunk>>4 = side; LDS block kb=(l&15) holds global px-block kb^(c&7).
#define STAGE_HALF(h)                                                         \
  {                                                                           \
    _Pragma("unroll") for (int q = 0; q < 4; ++q) {                           \
      const int ckk = (w << 2) + q;                                           \
      const int c = ((ckk & 15) << 2) + (l >> 4);                             \
      const size_t off = bb + ((size_t)c << 16) + px_blk + ((h) << 6) +       \
                         (((l & 15) ^ (c & 7)) << 2);                         \
      gload_lds16(((ckk >> 4) ? x2 : x1) + off, &buf[(h) & 1][ckk << 8]);     \
    }                                                                         \
  }

  STAGE_HALF(0);

#pragma unroll 1
  for (int h = 0; h < 8; ++h) {
    if (h == 0) {
      asm volatile("s_waitcnt vmcnt(0)" ::: "memory");
    } else {
      // outstanding: 4 stage(h) loads (oldest) + 16 stores from half h-1
      asm volatile("s_waitcnt vmcnt(16)" ::: "memory");
    }
    __builtin_amdgcn_s_barrier();
    __builtin_amdgcn_sched_barrier(0);
    if (h + 1 < 8) STAGE_HALF(h + 1);
    __builtin_amdgcn_sched_barrier(0);  // pin stage issue before compute

    const float* bufc = buf[h & 1];
    const float* bo = bufc + ((side ^ 1) << 12);  // cross input
    const float* bw = bufc + (side << 12);        // own side (residual)

    f32x4 acc[4];
#pragma unroll
    for (int n = 0; n < 4; ++n) {
#pragma unroll
      for (int r = 0; r < 4; ++r) {
        const int o = (n << 4) + (lg << 2) + r;
        acc[n][r] = cvr[(n << 2) + r] + bw[(o << 6) + ((pxb ^ (o & 7)) << 2) + pxi];
      }
    }

#pragma unroll
    for (int ks = 0; ks < 2; ++ks) {
      bf16x8 xh;
#pragma unroll
      for (int e = 0; e < 8; ++e) {
        const int rr = (ks << 5) + (lg << 3) + e;
        const float v = bo[(rr << 6) + ((pxb ^ (rr & 7)) << 2) + pxi];
        xh[e] = (short)(__float_as_uint(v) >> 16);
      }
#pragma unroll
      for (int n = 0; n < 4; ++n) {
        acc[n] = __builtin_amdgcn_mfma_f32_16x16x32_bf16(mh[n][ks], xh, acc[n], 0, 0, 0);
        acc[n] = __builtin_amdgcn_mfma_f32_16x16x32_bf16(ml[n][ks], xh, acc[n], 0, 0, 0);
      }
    }

    const size_t po = ((size_t)side << 24) + bb + px_blk + (h << 6) + px;
#pragma unroll
    for (int n = 0; n < 4; ++n) {
#pragma unroll
      for (int r = 0; r < 4; ++r) {
        const int o = (n << 4) + (lg << 2) + r;
        out[po + ((size_t)o << 16)] = acc[n][r];
      }
    }
  }
#undef STAGE_HALF
}

// ---------------------------------------------------------------------------
extern "C" void kernel_launch(void* const* d_in, const int* in_sizes, int n_in,
                              void* d_out, int out_size, void* d_ws, size_t ws_size,
                              hipStream_t stream) {
  const float* x1 = (const float*)d_in[0];
  const float* x2 = (const float*)d_in[1];
  float* ws = (float*)d_ws;
  float* out = (float*)d_out;

  k_gram<<<NBLK_GRAM, 512, 0, stream>>>(x1, x2, ws + GP_OFF, ws + SP_OFF);
  k_reduce<<<68, 256, 0, stream>>>(ws);
  k_mid<<<8, 256, 0, stream>>>(
      (const float*)d_in[2],  (const float*)d_in[3],   // w_q1, b_q1
      (const float*)d_in[4],  (const float*)d_in[5],   // w_k2, b_k2
      (const float*)d_in[6],  (const float*)d_in[7],   // w_v2, b_v2
      (const float*)d_in[14], (const float*)d_in[15],  // w_o1, b_o1
      (const float*)d_in[8],  (const float*)d_in[9],   // w_q2, b_q2
      (const float*)d_in[10], (const float*)d_in[11],  // w_k1, b_k1
      (const float*)d_in[12], (const float*)d_in[13],  // w_v1, b_v1
      (const float*)d_in[16], (const float*)d_in[17],  // w_o2, b_o2
      ws);
  k_apply<<<512, 512, 0, stream>>>(x1, x2, ws, out);
}

// Round 11
// 97.036 us; speedup vs baseline: 1.4883x; 1.0268x over previous
//
#include <hip/hip_runtime.h>

// ---------------------------------------------------------------------------
// SymmetricCrossAttention, B=4, C=64, H=W=256, HEADS=1.
// out1 = M1 X2 + c1 + X1, out2 = M2 X1 + c2 + X2 with M,c derived from
// G12 = X1 X2^T (64x64 per batch) + channel sums (k_gram/k_reduce/k_mid).
// R11 (tail round):
//  - k_reduce: 128-deep chains split into 2x64 (grid 136); k_mid sums the
//    halves during load (G halves -> MT region; s halves -> G_OFF region).
//  - k_gram: channel sums via MFMA ones-trick (s1 = X1*1, s2 = 1^T*X2, exact
//    hi+lo) -- removes the per-tile LDS re-read + shfl reduce.
//  - k_apply (MFMA R9) unchanged.
// ---------------------------------------------------------------------------

#define NPIX 65536
#define SCALE 0.125f
#define NBLK_GRAM 512      // 4 batches * 128 chunks (512 px each)

// workspace float offsets
#define GP_OFF  0                      // 512*4096 partial Grams (dead after
                                       // k_reduce; k_mid aliases MH/ML here)
#define SP_OFF  2097152                // 512*128 partial channel sums (s1|s2)
#define G_OFF   2162688                // R11: s-half sums, 2*1024 floats
#define S1_OFF  2179072                // (unused in R11)
#define S2_OFF  2179328                // (unused in R11)
#define MT_OFF  2179584                // R11: G halves, 2*16384 floats
#define CV_OFF  2212352                // 2*4*64
#define WS_FLOATS 2212864              // ~8.85 MB

typedef __attribute__((ext_vector_type(8))) short bf16x8;  // 4 VGPR A/B frag
typedef __attribute__((ext_vector_type(4))) float f32x4;   // 16x16 C/D frag

// ---- XOR-swizzled 64x64 fp32 LDS tile helpers (16B-block index ^ (row>>2)&7)
__device__ __forceinline__ int swzidx(int row, int k) {
  return (row << 6) + ((((k >> 2) ^ ((row >> 2) & 7)) << 2) | (k & 3));
}
__device__ __forceinline__ float ldswz1(const float* b, int row, int k) {
  return b[swzidx(row, k)];
}
__device__ __forceinline__ void stswz1(float* b, int row, int k, float v) {
  b[swzidx(row, k)] = v;
}
__device__ __forceinline__ float4 ldswz4f(const float* b, int row, int k) { // k%4==0
  return *(const float4*)(b + (row << 6) + ((((k >> 2) ^ ((row >> 2) & 7)) << 2)));
}
__device__ __forceinline__ void stswz4f(float* b, int row, int k, float4 v) {
  *(float4*)(b + (row << 6) + ((((k >> 2) ^ ((row >> 2) & 7)) << 2))) = v;
}

// ---- async global->LDS 16B (wave-uniform LDS base + lane*16; global per-lane)
__device__ __forceinline__ void gload_lds16(const float* g, float* l) {
  __builtin_amdgcn_global_load_lds(
      (const __attribute__((address_space(1))) unsigned int*)g,
      (__attribute__((address_space(3))) unsigned int*)l, 16, 0, 0);
}

// ---- fp32 -> bf16 hi/lo split (truncation; lo captures next 16 mantissa bits)
__device__ __forceinline__ void cvt_hilo(float4 p, float4 q, bf16x8& hi, bf16x8& lo) {
  float x[8] = {p.x, p.y, p.z, p.w, q.x, q.y, q.z, q.w};
#pragma unroll
  for (int j = 0; j < 8; ++j) {
    const unsigned u = __float_as_uint(x[j]);
    const float hf = __uint_as_float(u & 0xFFFF0000u);
    hi[j] = (short)(u >> 16);
    lo[j] = (short)(__float_as_uint(x[j] - hf) >> 16);
  }
}

// ---------------------------------------------------------------------------
// Gram kernel (MFMA, pipelined; R11 sums-via-MFMA): per batch, G12 = X1 X2^T.
// 512 blocks x 512 thr = 2 k-groups x 4 waves. Group g owns px half
// [g*256, +256) as 8 tiles of 32 px, double-buffered (2x16KB per group).
// Channel sums: accs1 += mfma(Ahi,1)+mfma(Alo,1) (rowsums of X1 strip);
// accs2 += mfma(1,Bhi)+mfma(1,Blo) at n==wl (rowsums of X2 strip). Exact.
__global__ __launch_bounds__(512) void k_gram(const float* __restrict__ x1,
                                              const float* __restrict__ x2,
                                              float* __restrict__ gp,
                                              float* __restrict__ sp) {
  __shared__ __align__(16) float lds[16384];
  const int tid = threadIdx.x;
  const int b = blockIdx.x >> 7;
  const int chunk = blockIdx.x & 127;

  const int w = tid >> 6;          // wave 0..7
  const int grp = w >> 2;          // k-group
  const int wl = w & 3;            // wave-in-group -> G row-block
  const int l = tid & 63;
  const int lrow = l & 15;         // A row / B col within 16
  const int lkg = l >> 4;          // k-group-of-8 within frag (0..3)
  const int arow = (wl << 4) + lrow;
  const size_t base = ((size_t)b << 22) + ((size_t)chunk << 9) + (grp << 8);

  f32x4 acc[4] = {};
  f32x4 accs1 = {}, accs2 = {};    // ones-trick channel-sum accumulators
  bf16x8 ONE;
#pragma unroll
  for (int j = 0; j < 8; ++j) ONE[j] = (short)0x3F80;

  // stage tile t of this group into buffer (t&1): 16 chunks of 1KB
  // (8 rows x 8 blocks each); wave wl: X1 chunks {2wl,2wl+1}, X2 same.
#define STAGE_T(t)                                                            \
  {                                                                           \
    _Pragma("unroll") for (int q = 0; q < 4; ++q) {                           \
      const int a = q >> 1;                                                   \
      const int ck = (wl << 1) | (q & 1);                                     \
      const int r = (ck << 3) + (l >> 3);                                     \
      const size_t off = base + ((t) << 5) + ((size_t)r << 16) +              \
                         (((l & 7) ^ (r & 7)) << 2);                          \
      gload_lds16((a ? x2 : x1) + off,                                        \
                  &lds[((grp << 2) + (((t) & 1) << 1) + a) << 11] + (ck << 8)); \
    }                                                                         \
  }

  STAGE_T(0);

#pragma unroll 1
  for (int t = 0; t < 8; ++t) {
    asm volatile("s_waitcnt vmcnt(0)" ::: "memory");  // own stage(t) done
    __builtin_amdgcn_s_barrier();                     // all waves' stage(t) done
    __builtin_amdgcn_sched_barrier(0);
    if (t + 1 < 8) STAGE_T(t + 1);                    // overlaps compute(t)
    __builtin_amdgcn_sched_barrier(0);

    const int d = t & 1;
    const float* R1 = &lds[((grp << 2) + (d << 1)) << 11];
    const float* R2 = R1 + 2048;

    // MFMA: one K=32 step per tile
    const int kb0 = lkg << 1;
    bf16x8 ahi, alo;
    {
      const float4 p = *(const float4*)&R1[(arow << 5) + ((kb0 ^ (arow & 7)) << 2)];
      const float4 q2 = *(const float4*)&R1[(arow << 5) + (((kb0 + 1) ^ (arow & 7)) << 2)];
      cvt_hilo(p, q2, ahi, alo);
    }
    accs1 = __builtin_amdgcn_mfma_f32_16x16x32_bf16(ahi, ONE, accs1, 0, 0, 0);
    accs1 = __builtin_amdgcn_mfma_f32_16x16x32_bf16(alo, ONE, accs1, 0, 0, 0);
#pragma unroll
    for (int n = 0; n < 4; ++n) {
      const int brow = (n << 4) + lrow;
      const float4 p = *(const float4*)&R2[(brow << 5) + ((kb0 ^ (brow & 7)) << 2)];
      const float4 q2 = *(const float4*)&R2[(brow << 5) + (((kb0 + 1) ^ (brow & 7)) << 2)];
      bf16x8 bhi, blo;
      cvt_hilo(p, q2, bhi, blo);
      acc[n] = __builtin_amdgcn_mfma_f32_16x16x32_bf16(ahi, bhi, acc[n], 0, 0, 0);
      acc[n] = __builtin_amdgcn_mfma_f32_16x16x32_bf16(ahi, blo, acc[n], 0, 0, 0);
      acc[n] = __builtin_amdgcn_mfma_f32_16x16x32_bf16(alo, bhi, acc[n], 0, 0, 0);
      if (n == wl) {  // wave-uniform branch: this wave owns B rows wl*16..+16
        accs2 = __builtin_amdgcn_mfma_f32_16x16x32_bf16(ONE, bhi, accs2, 0, 0, 0);
        accs2 = __builtin_amdgcn_mfma_f32_16x16x32_bf16(ONE, blo, accs2, 0, 0, 0);
      }
    }
  }
#undef STAGE_T

  // ---- cross-group combine (tiles all consumed; reuse LDS front) ----
  // accs1: D[r][c] = rowsum(X1 row arow-strip), cols identical; row = lkg*4+r.
  // accs2: D[r][c] = rowsum(X2 row wl*16+col), rows identical; col = lrow.
  __syncthreads();
  float* exA = lds;                               // 4096 floats acc exchange
  float* exS = lds + 4096;                        // 128 floats sum exchange
  if (grp == 1) {
#pragma unroll
    for (int n = 0; n < 4; ++n) {
      *(float4*)&exA[((n << 8) + (wl << 6) + l) << 2] =
          make_float4(acc[n][0], acc[n][1], acc[n][2], acc[n][3]);
    }
    if (lrow == 0) {
#pragma unroll
      for (int r = 0; r < 4; ++r) exS[(wl << 4) + (lkg << 2) + r] = accs1[r];
    }
    if (l < 16) exS[64 + (wl << 4) + lrow] = accs2[0];
  }
  __syncthreads();
  if (grp == 0) {
#pragma unroll
    for (int n = 0; n < 4; ++n) {
      const float4 v = *(const float4*)&exA[((n << 8) + (wl << 6) + l) << 2];
      acc[n][0] += v.x; acc[n][1] += v.y; acc[n][2] += v.z; acc[n][3] += v.w;
    }
    float* spb = sp + (blockIdx.x << 7);
    if (lrow == 0) {
#pragma unroll
      for (int r = 0; r < 4; ++r) {
        const int c = (wl << 4) + (lkg << 2) + r;
        spb[c] = accs1[r] + exS[c];
      }
    }
    if (l < 16) {
      const int c = (wl << 4) + lrow;
      spb[64 + c] = accs2[0] + exS[64 + c];
    }
    // G partial: C/D layout col=lane&15, row=(lane>>4)*4+reg (m89-verified)
    float* g = gp + ((size_t)blockIdx.x << 12);
#pragma unroll
    for (int n = 0; n < 4; ++n) {
#pragma unroll
      for (int r = 0; r < 4; ++r) {
        g[(((wl << 4) + (lkg << 2) + r) << 6) + (n << 4) + lrow] = acc[n][r];
      }
    }
  }
}

// ---------------------------------------------------------------------------
// Reduce (R11): split 128-deep sums into 2 halves of 64. Grid 136:
// blocks 0..127: G halves -> ws[MT_OFF + half*16384 + idx];
// blocks 128..135: s halves -> ws[G_OFF + half*1024 + b*128 + c].
__global__ __launch_bounds__(256) void k_reduce(float* __restrict__ ws) {
  const int g = blockIdx.x;
  const int tid = threadIdx.x;
  if (g < 128) {
    const int half = g >> 6;
    const int idx = ((g & 63) << 8) + tid;     // 0..16383
    const int b = idx >> 12, e = idx & 4095;
    const float* p = ws + GP_OFF + ((size_t)((b << 7) + (half << 6)) << 12) + e;
    float a = 0.f;
#pragma unroll 8
    for (int k = 0; k < 64; ++k) a += p[(size_t)k << 12];
    ws[MT_OFF + (half << 14) + idx] = a;
  } else {
    const int q = g - 128;                     // 0..7 = b*2 + half
    if (tid < 128) {
      const int b = q >> 1, half = q & 1;
      const float* p = ws + SP_OFF + (((b << 7) + (half << 6)) << 7) + tid;
      float a = 0.f;
#pragma unroll 8
      for (int k = 0; k < 64; ++k) a += p[k << 7];
      ws[G_OFF + (half << 10) + (b << 7) + tid] = a;
    }
  }
}

// ---------------------------------------------------------------------------
// 64x64 fp32 matmul in swizzled LDS. D[c][d] = sum_k A[c][k] * (TRANSB ? B[d][k] : B[k][d])
template <bool TRANSB>
__device__ __forceinline__ void mm64(const float* __restrict__ A, const float* __restrict__ B,
                                     float* __restrict__ D, int tid) {
  const int c0 = (tid >> 4) << 2;
  const int d0 = (tid & 15) << 2;
  float acc[4][4] = {{0.f}};
#pragma unroll
  for (int kb = 0; kb < 64; kb += 4) {
    float4 a[4];
#pragma unroll
    for (int i = 0; i < 4; ++i) a[i] = ldswz4f(A, c0 + i, kb);
    if (TRANSB) {
#pragma unroll
      for (int j = 0; j < 4; ++j) {
        const float4 bj = ldswz4f(B, d0 + j, kb);
#pragma unroll
        for (int i = 0; i < 4; ++i) {
          acc[i][j] += a[i].x * bj.x + a[i].y * bj.y + a[i].z * bj.z + a[i].w * bj.w;
        }
      }
    } else {
#pragma unroll
      for (int r = 0; r < 4; ++r) {
        const float4 q = ldswz4f(B, kb + r, d0);
        const float br[4] = {q.x, q.y, q.z, q.w};
#pragma unroll
        for (int i = 0; i < 4; ++i) {
          const float av = (r == 0) ? a[i].x : (r == 1) ? a[i].y : (r == 2) ? a[i].z : a[i].w;
#pragma unroll
          for (int j = 0; j < 4; ++j) acc[i][j] += av * br[j];
        }
      }
    }
  }
#pragma unroll
  for (int i = 0; i < 4; ++i) {
    stswz4f(D, c0 + i, d0, make_float4(acc[i][0], acc[i][1], acc[i][2], acc[i][3]));
  }
}

// M = A @ B (non-trans); store row-major as bf16 hi/lo shorts (exact split).
__device__ __forceinline__ void mm64_store_hilo(const float* __restrict__ A,
                                                const float* __restrict__ B,
                                                unsigned short* __restrict__ MH,
                                                unsigned short* __restrict__ ML,
                                                int tid) {
  const int c0 = (tid >> 4) << 2;
  const int d0 = (tid & 15) << 2;
  float acc[4][4] = {{0.f}};
#pragma unroll
  for (int kb = 0; kb < 64; kb += 4) {
    float4 a[4];
#pragma unroll
    for (int i = 0; i < 4; ++i) a[i] = ldswz4f(A, c0 + i, kb);
#pragma unroll
    for (int r = 0; r < 4; ++r) {
      const float4 q = ldswz4f(B, kb + r, d0);
      const float br[4] = {q.x, q.y, q.z, q.w};
#pragma unroll
      for (int i = 0; i < 4; ++i) {
        const float av = (r == 0) ? a[i].x : (r == 1) ? a[i].y : (r == 2) ? a[i].z : a[i].w;
#pragma unroll
        for (int j = 0; j < 4; ++j) acc[i][j] += av * br[j];
      }
    }
  }
#pragma unroll
  for (int i = 0; i < 4; ++i) {
#pragma unroll
    for (int j = 0; j < 4; ++j) {
      const float v = acc[i][j];
      const unsigned u = __float_as_uint(v);
      const float hf = __uint_as_float(u & 0xFFFF0000u);
      const int idx = ((c0 + i) << 6) + d0 + j;
      MH[idx] = (unsigned short)(u >> 16);
      ML[idx] = (unsigned short)(__float_as_uint(v - hf) >> 16);
    }
  }
}

__device__ __forceinline__ void load64x64(const float* __restrict__ g, float* __restrict__ lds, int tid) {
#pragma unroll
  for (int r = 0; r < 4; ++r) {
    const int idx = (r << 8) + tid;
    const int row = idx >> 4;
    const int b4 = (idx & 15) << 2;
    stswz4f(lds, row, b4, *(const float4*)(g + (row << 6) + b4));
  }
}

// sum two G halves while loading into swizzled LDS
__device__ __forceinline__ void load64x64sum(const float* __restrict__ g0,
                                             const float* __restrict__ g1,
                                             float* __restrict__ lds, int tid) {
#pragma unroll
  for (int r = 0; r < 4; ++r) {
    const int idx = (r << 8) + tid;
    const int row = idx >> 4;
    const int b4 = (idx & 15) << 2;
    const float4 a = *(const float4*)(g0 + (row << 6) + b4);
    const float4 b = *(const float4*)(g1 + (row << 6) + b4);
    stswz4f(lds, row, b4, make_float4(a.x + b.x, a.y + b.y, a.z + b.z, a.w + b.w));
  }
}

// ---------------------------------------------------------------------------
// Middle kernel: 8 blocks = 4 batches x 2 sides. Builds logits from G/s
// (R11: sums the reduce halves while loading), softmax, then M (bf16 hi/lo
// into GP alias) and c vectors into ws.
__global__ __launch_bounds__(256) void k_mid(
    const float* __restrict__ wq1, const float* __restrict__ bq1,
    const float* __restrict__ wk2, const float* __restrict__ bk2,
    const float* __restrict__ wv2, const float* __restrict__ bv2,
    const float* __restrict__ wo1, const float* __restrict__ bo1,
    const float* __restrict__ wq2, const float* __restrict__ bq2,
    const float* __restrict__ wk1, const float* __restrict__ bk1,
    const float* __restrict__ wv1, const float* __restrict__ bv1,
    const float* __restrict__ wo2, const float* __restrict__ bo2,
    float* __restrict__ ws) {
  __shared__ __align__(16) float LA[4096];
  __shared__ __align__(16) float LB[4096];
  __shared__ __align__(16) float LC[4096];
  __shared__ __align__(16) float LD[4096];
  __shared__ float vsq[64], vsk[64], vaq[64], vkk[64], vcv[64];

  const int tid = threadIdx.x;
  const int b = blockIdx.x >> 1;
  const int side = blockIdx.x & 1;

  const float *Wq, *Bq, *Wk, *Bk, *Wv, *Bv, *Wo, *Bo;
  if (side == 0) {
    Wq = wq1; Bq = bq1; Wk = wk2; Bk = bk2; Wv = wv2; Bv = bv2; Wo = wo1; Bo = bo1;
  } else {
    Wq = wq2; Bq = bq2; Wk = wk1; Bk = bk1; Wv = wv1; Bv = bv1; Wo = wo2; Bo = bo2;
  }
  const int job = (side << 2) + b;
  unsigned short* MH = (unsigned short*)(ws + GP_OFF) + (job << 12);
  unsigned short* ML = (unsigned short*)(ws + GP_OFF) + (8 << 12) + (job << 12);
  float* Cv = ws + CV_OFF + (job << 6);

  if (tid < 64) {  // channel sums: fold the two reduce halves
    const float* sh = ws + G_OFF;
    const float s1v = sh[(b << 7) + tid] + sh[1024 + (b << 7) + tid];
    const float s2v = sh[(b << 7) + 64 + tid] + sh[1024 + (b << 7) + 64 + tid];
    vsq[tid] = (side == 0) ? s1v : s2v;
    vsk[tid] = (side == 0) ? s2v : s1v;
  }
  load64x64sum(ws + MT_OFF + (b << 12), ws + MT_OFF + 16384 + (b << 12), LA, tid);
  load64x64(Wq, LB, tid);
  __syncthreads();
  if (tid < 64) {  // aq = Wq @ sq
    float a = 0.f;
    for (int k = 0; k < 64; ++k) a += ldswz1(LB, tid, k) * vsq[k];
    vaq[tid] = a;
  }
  // T = Wq @ G (side0)  or  Wq @ G^T (side1)
  if (side == 0) mm64<false>(LB, LA, LC, tid);
  else           mm64<true >(LB, LA, LC, tid);
  __syncthreads();
  load64x64(Wk, LB, tid);
  __syncthreads();
  if (tid < 64) {  // kk = Wk @ sk
    float a = 0.f;
    for (int k = 0; k < 64; ++k) a += ldswz1(LB, tid, k) * vsk[k];
    vkk[tid] = a;
  }
  mm64<true>(LC, LB, LD, tid);  // S = T @ Wk^T
  __syncthreads();
  // assemble logits: S = scale*(S + aq[c]*bk[d] + bq[c]*(kk[d] + N*bk[d]))
#pragma unroll
  for (int t = 0; t < 16; ++t) {
    const int idx = (t << 8) + tid;
    const int c = idx >> 6, d = idx & 63;
    const float bkv = Bk[d], bqv = Bq[c];
    float v = ldswz1(LD, c, d);
    v = SCALE * (v + vaq[c] * bkv + bqv * (vkk[d] + 65536.f * bkv));
    stswz1(LD, c, d, v);
  }
  __syncthreads();
  {  // row softmax, 4 lanes per row
    const int row = tid >> 2, q = tid & 3;
    float ev[16];
    float mx = -3.4e38f;
#pragma unroll
    for (int t = 0; t < 16; ++t) { ev[t] = ldswz1(LD, row, q + (t << 2)); mx = fmaxf(mx, ev[t]); }
    mx = fmaxf(mx, __shfl_xor(mx, 1));
    mx = fmaxf(mx, __shfl_xor(mx, 2));
    float sm = 0.f;
#pragma unroll
    for (int t = 0; t < 16; ++t) { ev[t] = __expf(ev[t] - mx); sm += ev[t]; }
    sm += __shfl_xor(sm, 1);
    sm += __shfl_xor(sm, 2);
    const float inv = 1.f / sm;
#pragma unroll
    for (int t = 0; t < 16; ++t) stswz1(LD, row, q + (t << 2), ev[t] * inv);
  }
  __syncthreads();
  if (tid < 64) {  // cv = attn @ bv
    float a = 0.f;
    for (int d = 0; d < 64; ++d) a += ldswz1(LD, tid, d) * Bv[d];
    vcv[tid] = a;
  }
  load64x64(Wv, LB, tid);
  __syncthreads();
  mm64<false>(LD, LB, LC, tid);  // U = attn @ Wv
  __syncthreads();
  load64x64(Wo, LB, tid);
  __syncthreads();
  mm64_store_hilo(LB, LC, MH, ML, tid);  // M = Wo @ U -> bf16 hi/lo
  if (tid < 64) {                // c = Wo @ cv + bo
    float a = 0.f;
    for (int c = 0; c < 64; ++c) a += ldswz1(LB, tid, c) * vcv[c];
    Cv[tid] = a + Bo[tid];
  }
}

// ---------------------------------------------------------------------------
// Apply kernel (MFMA, unchanged from R9): 512 blocks x 512 thr; 8 half-tiles
// of 64 px, double-buffered; M-frags resident in VGPRs; 2 mfma/octile/kstep.
__global__ __launch_bounds__(512) void k_apply(const float* __restrict__ x1,
                                               const float* __restrict__ x2,
                                               const float* __restrict__ ws,
                                               float* __restrict__ out) {
  __shared__ __align__(16) float buf[2][8192];  // [dbuf][side*4096 + ch*64 + px(swz)]
  const int tid = threadIdx.x;
  const int b = blockIdx.x >> 7;
  const int px_blk = (blockIdx.x & 127) << 9;   // 512 px per block
  const size_t bb = (size_t)b << 22;

  const int w = tid >> 6;
  const int l = tid & 63;
  const int wu = __builtin_amdgcn_readfirstlane(w);
  const int side = wu >> 2;
  const int p16 = (wu & 3) << 4;                // px16 base within 64-px half
  const int job = (side << 2) + b;
  const int lr = l & 15;                        // M-row / px within 16
  const int lg = l >> 4;                        // k-group / D-row group
  const int px = p16 + lr;                      // px within 64-px half
  const int pxb = px >> 2;                      // 16B block of px
  const int pxi = px & 3;

  // M fragments (resident): 4 octiles x 2 ksteps x {hi,lo}
  const unsigned short* MH = (const unsigned short*)(ws + GP_OFF) + (job << 12);
  const unsigned short* ML = (const unsigned short*)(ws + GP_OFF) + (8 << 12) + (job << 12);
  bf16x8 mh[4][2], ml[4][2];
#pragma unroll
  for (int n = 0; n < 4; ++n) {
#pragma unroll
    for (int ks = 0; ks < 2; ++ks) {
      const int idx = (((n << 4) + lr) << 6) + (ks << 5) + (lg << 3);
      mh[n][ks] = *(const bf16x8*)&MH[idx];
      ml[n][ks] = *(const bf16x8*)&ML[idx];
    }
  }
  // bias for this thread's 16 output elements: o = n*16 + lg*4 + r
  const float* Cvp = ws + CV_OFF + (job << 6);
  float cvr[16];
#pragma unroll
  for (int n = 0; n < 4; ++n)
#pragma unroll
    for (int r = 0; r < 4; ++r) cvr[(n << 2) + r] = Cvp[(n << 4) + (lg << 2) + r];

  // stage half h into buf[h&1]: 32 chunks of 1KB (4 ch-rows x 64px);
  // chunk>>4 = side; LDS block kb=(l&15) holds global px-block kb^(c&7).
#define STAGE_HALF(h)                                                         \
  {                                                                           \
    _Pragma("unroll") for (int q = 0; q < 4; ++q) {                           \
      const int ckk = (w << 2) + q;                                           \
      const int c = ((ckk & 15) << 2) + (l >> 4);                             \
      const size_t off = bb + ((size_t)c << 16) + px_blk + ((h) << 6) +       \
                         (((l & 15) ^ (c & 7)) << 2);                         \
      gload_lds16(((ckk >> 4) ? x2 : x1) + off, &buf[(h) & 1][ckk << 8]);     \
    }                                                                         \
  }

  STAGE_HALF(0);

#pragma unroll 1
  for (int h = 0; h < 8; ++h) {
    if (h == 0) {
      asm volatile("s_waitcnt vmcnt(0)" ::: "memory");
    } else {
      // outstanding: 4 stage(h) loads (oldest) + 16 stores from half h-1
      asm volatile("s_waitcnt vmcnt(16)" ::: "memory");
    }
    __builtin_amdgcn_s_barrier();
    __builtin_amdgcn_sched_barrier(0);
    if (h + 1 < 8) STAGE_HALF(h + 1);
    __builtin_amdgcn_sched_barrier(0);  // pin stage issue before compute

    const float* bufc = buf[h & 1];
    const float* bo = bufc + ((side ^ 1) << 12);  // cross input
    const float* bw = bufc + (side << 12);        // own side (residual)

    f32x4 acc[4];
#pragma unroll
    for (int n = 0; n < 4; ++n) {
#pragma unroll
      for (int r = 0; r < 4; ++r) {
        const int o = (n << 4) + (lg << 2) + r;
        acc[n][r] = cvr[(n << 2) + r] + bw[(o << 6) + ((pxb ^ (o & 7)) << 2) + pxi];
      }
    }

#pragma unroll
    for (int ks = 0; ks < 2; ++ks) {
      bf16x8 xh;
#pragma unroll
      for (int e = 0; e < 8; ++e) {
        const int rr = (ks << 5) + (lg << 3) + e;
        const float v = bo[(rr << 6) + ((pxb ^ (rr & 7)) << 2) + pxi];
        xh[e] = (short)(__float_as_uint(v) >> 16);
      }
#pragma unroll
      for (int n = 0; n < 4; ++n) {
        acc[n] = __builtin_amdgcn_mfma_f32_16x16x32_bf16(mh[n][ks], xh, acc[n], 0, 0, 0);
        acc[n] = __builtin_amdgcn_mfma_f32_16x16x32_bf16(ml[n][ks], xh, acc[n], 0, 0, 0);
      }
    }

    const size_t po = ((size_t)side << 24) + bb + px_blk + (h << 6) + px;
#pragma unroll
    for (int n = 0; n < 4; ++n) {
#pragma unroll
      for (int r = 0; r < 4; ++r) {
        const int o = (n << 4) + (lg << 2) + r;
        out[po + ((size_t)o << 16)] = acc[n][r];
      }
    }
  }
#undef STAGE_HALF
}

// ---------------------------------------------------------------------------
extern "C" void kernel_launch(void* const* d_in, const int* in_sizes, int n_in,
                              void* d_out, int out_size, void* d_ws, size_t ws_size,
                              hipStream_t stream) {
  const float* x1 = (const float*)d_in[0];
  const float* x2 = (const float*)d_in[1];
  float* ws = (float*)d_ws;
  float* out = (float*)d_out;

  k_gram<<<NBLK_GRAM, 512, 0, stream>>>(x1, x2, ws + GP_OFF, ws + SP_OFF);
  k_reduce<<<136, 256, 0, stream>>>(ws);
  k_mid<<<8, 256, 0, stream>>>(
      (const float*)d_in[2],  (const float*)d_in[3],   // w_q1, b_q1
      (const float*)d_in[4],  (const float*)d_in[5],   // w_k2, b_k2
      (const float*)d_in[6],  (const float*)d_in[7],   // w_v2, b_v2
      (const float*)d_in[14], (const float*)d_in[15],  // w_o1, b_o1
      (const float*)d_in[8],  (const float*)d_in[9],   // w_q2, b_q2
      (const float*)d_in[10], (const float*)d_in[11],  // w_k1, b_k1
      (const float*)d_in[12], (const float*)d_in[13],  // w_v1, b_v1
      (const float*)d_in[16], (const float*)d_in[17],  // w_o2, b_o2
      ws);
  k_apply<<<512, 512, 0, stream>>>(x1, x2, ws, out);
}